// Round 3
// baseline (2443.835 us; speedup 1.0000x reference)
//
#include <hip/hip_runtime.h>
#include <hip/hip_bf16.h>
#include <math.h>

#define NPOS 4900
#define NG1  708
#define NG2  4192
#define INF  512
#define OUTF 256
#define JPAD 4904       // padded j-stride for BcP planes (mult of 8, >= 4900)
#define JS   384        // logits slab width
#define NSLAB 13        // ceil(4900/384)

// ---------------------------------------------------------------------------
// K0: rp = r @ Wr + br  (4x256); store S[0]=rp[ridx], S[1]=rp[2], S[2]=rp[3]
// ---------------------------------------------------------------------------
__global__ __launch_bounds__(256) void k0_rp(
    const float* __restrict__ r, const float* __restrict__ Wr,
    const float* __restrict__ br, const int* __restrict__ flagp,
    float* __restrict__ S)
{
    __shared__ float rsh[1024];
    int t = threadIdx.x;
    for (int i = t; i < 1024; i += 256) rsh[i] = r[i];
    __syncthreads();
    float a0 = 0.f, a1 = 0.f, a2 = 0.f, a3 = 0.f;
    for (int c = 0; c < 256; ++c) {
        float w = Wr[c * 256 + t];
        a0 += rsh[c] * w;
        a1 += rsh[256 + c] * w;
        a2 += rsh[512 + c] * w;
        a3 += rsh[768 + c] * w;
    }
    float b = br[t];
    a0 += b; a1 += b; a2 += b; a3 += b;
    int ridx = (flagp[0] != 0) ? 1 : 0;
    S[t]         = ridx ? a1 : a0;
    S[256 + t]   = a2;
    S[512 + t]   = a3;
}

// ---------------------------------------------------------------------------
// K1: fused projections hQ/hK/hV/H = feature @ {Wq,Wk,Wv,Ww} + bias
// ---------------------------------------------------------------------------
__global__ __launch_bounds__(256) void k1_proj(
    const float* __restrict__ feat,
    const float* __restrict__ Wq, const float* __restrict__ bq,
    const float* __restrict__ Wk, const float* __restrict__ bk,
    const float* __restrict__ Wv, const float* __restrict__ bv,
    const float* __restrict__ Ww, const float* __restrict__ bw,
    float* __restrict__ hQ, float* __restrict__ hK,
    float* __restrict__ hV, float* __restrict__ Hb)
{
    __shared__ float AT[16][68];    // [k][m]
    __shared__ float Bs[16][132];   // [k][n]
    int t = threadIdx.x;
    int mat = blockIdx.x >> 1;
    int n0  = (blockIdx.x & 1) * 128;
    int m0  = blockIdx.y * 64;
    const float* W; const float* bias; float* dst;
    switch (mat) {
        case 0:  W = Wq; bias = bq; dst = hQ; break;
        case 1:  W = Wk; bias = bk; dst = hK; break;
        case 2:  W = Wv; bias = bv; dst = hV; break;
        default: W = Ww; bias = bw; dst = Hb; break;
    }
    float acc[4][8];
#pragma unroll
    for (int i = 0; i < 4; ++i)
#pragma unroll
        for (int j = 0; j < 8; ++j) acc[i][j] = 0.f;
    int mg = (t >> 4) * 4, jg = (t & 15) * 8;
    int am = t & 63, ak = (t >> 6) * 4;
    int bkk = t >> 4, bn = (t & 15) * 8;
    for (int k0 = 0; k0 < INF; k0 += 16) {
        __syncthreads();
        {
            int row = m0 + am;
            float4 v = make_float4(0.f, 0.f, 0.f, 0.f);
            if (row < NPOS) v = *(const float4*)(feat + (size_t)row * INF + k0 + ak);
            AT[ak + 0][am] = v.x; AT[ak + 1][am] = v.y;
            AT[ak + 2][am] = v.z; AT[ak + 3][am] = v.w;
        }
        {
            const float* p = W + (size_t)(k0 + bkk) * OUTF + n0 + bn;
            float4 u0 = *(const float4*)p;
            float4 u1 = *(const float4*)(p + 4);
            *(float4*)&Bs[bkk][bn]     = u0;
            *(float4*)&Bs[bkk][bn + 4] = u1;
        }
        __syncthreads();
#pragma unroll
        for (int kk = 0; kk < 16; ++kk) {
            float4 a  = *(const float4*)&AT[kk][mg];
            float4 b0 = *(const float4*)&Bs[kk][jg];
            float4 b1 = *(const float4*)&Bs[kk][jg + 4];
            float av[4] = {a.x, a.y, a.z, a.w};
            float bv_[8] = {b0.x, b0.y, b0.z, b0.w, b1.x, b1.y, b1.z, b1.w};
#pragma unroll
            for (int i = 0; i < 4; ++i)
#pragma unroll
                for (int j = 0; j < 8; ++j) acc[i][j] += av[i] * bv_[j];
        }
    }
#pragma unroll
    for (int i = 0; i < 4; ++i) {
        int row = m0 + mg + i;
        if (row < NPOS) {
#pragma unroll
            for (int j = 0; j < 8; ++j) {
                int n = n0 + jg + j;
                dst[(size_t)row * OUTF + n] = acc[i][j] + bias[n];
            }
        }
    }
}

// ---------------------------------------------------------------------------
// K2: BcP[part][g*256 + h*64+dd][j] = sum_k A[m][k] * adj[rowoff+k][j]
//     A[m][k] = hKpart[(h*L+k)*64+dd] * 0.5 * S[g+part][(k&3)*64+dd]
// Tile: M=256 (one g, 4 heads), N=64, BK=16.  Grid (77, 2=g, 2=part).
// ---------------------------------------------------------------------------
__global__ __launch_bounds__(256) void k2_pgemm(
    const float* __restrict__ hK, const float* __restrict__ adj,
    const float* __restrict__ S,
    float* __restrict__ BcP0, float* __restrict__ BcP1)
{
    __shared__ float As[16][264];   // [kk][m]  m=256
    __shared__ float Bs[16][72];    // [kk][j]  j=64
    int t = threadIdx.x;
    int j0 = blockIdx.x * 64;
    int g  = blockIdx.y;
    int part = blockIdx.z;
    int L = part ? NG2 : NG1;
    const float* kflat = hK + (part ? (size_t)NG1 * OUTF : 0);
    const float* sv = S + (g + part) * 256;
    int rowoff = part ? NG1 : 0;
    float* dst = (part ? BcP1 : BcP0) + (size_t)(g * 256) * JPAD;

    float acc[8][8];
#pragma unroll
    for (int i = 0; i < 8; ++i)
#pragma unroll
        for (int j = 0; j < 8; ++j) acc[i][j] = 0.f;
    int mgi = t >> 3, ng = t & 7;         // mgi 0..31 (m=mgi*8), ng 0..7 (j=ng*8)
    int Ksteps = (L + 15) >> 4;

    for (int ks = 0; ks < Ksteps; ++ks) {
        int k0 = ks * 16;
        __syncthreads();
        // A stage: 1024 float4 slots (16k x 256m), 4 per thread
#pragma unroll
        for (int i = 0; i < 4; ++i) {
            int s = t + i * 256;
            int kk = s >> 6, m4 = (s & 63) * 4;
            int kv = k0 + kk;
            float4 v = make_float4(0.f, 0.f, 0.f, 0.f);
            if (kv < L) {
                int h = m4 >> 6, dd = m4 & 63;
                float4 x  = *(const float4*)(kflat + ((size_t)(h * L + kv)) * 64 + dd);
                float4 s4 = *(const float4*)(sv + (kv & 3) * 64 + dd);
                v = make_float4(0.5f * x.x * s4.x, 0.5f * x.y * s4.y,
                                0.5f * x.z * s4.z, 0.5f * x.w * s4.w);
            }
            *(float4*)&As[kk][m4] = v;
        }
        // B stage: 16k x 64j, 1 float4 per thread
        {
            int kk = t >> 4, c4 = (t & 15) * 4;
            int kv = k0 + kk;
            int col = j0 + c4;
            float4 v = make_float4(0.f, 0.f, 0.f, 0.f);
            if (kv < L) {
                const float* p = adj + (size_t)(rowoff + kv) * NPOS + col;
                if (col + 3 < NPOS) v = *(const float4*)p;
                else {
                    v.x = (col + 0 < NPOS) ? p[0] : 0.f;
                    v.y = (col + 1 < NPOS) ? p[1] : 0.f;
                    v.z = (col + 2 < NPOS) ? p[2] : 0.f;
                    v.w = (col + 3 < NPOS) ? p[3] : 0.f;
                }
            }
            *(float4*)&Bs[kk][c4] = v;
        }
        __syncthreads();
#pragma unroll
        for (int kk = 0; kk < 16; ++kk) {
            float4 a0 = *(const float4*)&As[kk][mgi * 8];
            float4 a1 = *(const float4*)&As[kk][mgi * 8 + 4];
            float4 b0 = *(const float4*)&Bs[kk][ng * 8];
            float4 b1 = *(const float4*)&Bs[kk][ng * 8 + 4];
            float av[8] = {a0.x, a0.y, a0.z, a0.w, a1.x, a1.y, a1.z, a1.w};
            float bv_[8] = {b0.x, b0.y, b0.z, b0.w, b1.x, b1.y, b1.z, b1.w};
#pragma unroll
            for (int i = 0; i < 8; ++i)
#pragma unroll
                for (int j = 0; j < 8; ++j) acc[i][j] += av[i] * bv_[j];
        }
    }
#pragma unroll
    for (int i = 0; i < 8; ++i) {
        int m = mgi * 8 + i;
        float* drow = dst + (size_t)m * JPAD + j0 + ng * 8;
        int colb = j0 + ng * 8;
        if (colb + 7 < NPOS) {
            *(float4*)drow       = make_float4(acc[i][0], acc[i][1], acc[i][2], acc[i][3]);
            *(float4*)(drow + 4) = make_float4(acc[i][4], acc[i][5], acc[i][6], acc[i][7]);
        } else {
#pragma unroll
            for (int j = 0; j < 8; ++j)
                if (colb + j < NPOS) drow[j] = acc[i][j];
        }
    }
}

// ---------------------------------------------------------------------------
// K3a: logits slab GEMM.  LG[h][pos][jloc] = Q~[h,pos][0:128] . BcP[:, j0+jloc]
// K<64 from BcP0, K>=64 from BcP1.  Tile M=128, N=128, K=128.
// ---------------------------------------------------------------------------
__global__ __launch_bounds__(256) void k3a_logits(
    const float* __restrict__ hQ, const float* __restrict__ S,
    const float* __restrict__ BcP0, const float* __restrict__ BcP1,
    float* __restrict__ LG, int j0)
{
    __shared__ float As[16][132];    // [kk][m]
    __shared__ float BsA[16][68];    // cols jg..jg+3
    __shared__ float BsB[16][68];    // cols jg+4..jg+7
    int t = threadIdx.x;
    int n0 = blockIdx.x * 128;       // 0,128,256 within slab
    int y = blockIdx.y;              // 156 = 4h * 39
    int h = y / 39, rr = y % 39;
    int g, tile;
    if (rr < 6) { g = 0; tile = rr; } else { g = 1; tile = rr - 6; }
    int Lg = g ? NG2 : NG1;
    int vbase = g ? NG1 * OUTF : 0;
    int posbase = g ? NG1 : 0;
    int q0 = tile * 128;

    float acc[8][8];
#pragma unroll
    for (int i = 0; i < 8; ++i)
#pragma unroll
        for (int j = 0; j < 8; ++j) acc[i][j] = 0.f;
    int mg = (t >> 4) * 8, jg = (t & 15) * 8;
    int u = t & 15;
    int bkk = t >> 4;

    for (int k0 = 0; k0 < 128; k0 += 16) {
        int p = k0 >> 6;
        __syncthreads();
        // stage A (Q scaled): 512 float4 slots, 2 per thread
#pragma unroll
        for (int i = 0; i < 2; ++i) {
            int s = t + i * 256;
            int m = s >> 2, kq = (s & 3) * 4;
            int d = (k0 & 63) + kq;
            int ql = q0 + m;
            float4 v = make_float4(0.f, 0.f, 0.f, 0.f);
            if (ql < Lg) {
                float4 qv = *(const float4*)(hQ + vbase + (size_t)(h * Lg + ql) * 64 + d);
                float4 sv = *(const float4*)(S + (g + p) * 256 + (ql & 3) * 64 + d);
                v = make_float4(qv.x * sv.x, qv.y * sv.y, qv.z * sv.z, qv.w * sv.w);
            }
            As[kq + 0][m] = v.x; As[kq + 1][m] = v.y;
            As[kq + 2][m] = v.z; As[kq + 3][m] = v.w;
        }
        // stage B from part plane (de-interleaved)
        {
            const float* plane = p ? BcP1 : BcP0;
            int row = (g * 4 + h) * 64 + (k0 & 63) + bkk;
            int col = j0 + n0 + u * 8;
            float4 c0 = make_float4(0.f, 0.f, 0.f, 0.f);
            float4 c1 = make_float4(0.f, 0.f, 0.f, 0.f);
            if (col + 7 < JPAD) {
                const float* pp = plane + (size_t)row * JPAD + col;
                c0 = *(const float4*)pp;
                c1 = *(const float4*)(pp + 4);
            }
            *(float4*)&BsA[bkk][u * 4] = c0;
            *(float4*)&BsB[bkk][u * 4] = c1;
        }
        __syncthreads();
#pragma unroll
        for (int kk = 0; kk < 16; ++kk) {
            float4 a0 = *(const float4*)&As[kk][mg];
            float4 a1 = *(const float4*)&As[kk][mg + 4];
            float4 b0 = *(const float4*)&BsA[kk][u * 4];
            float4 b1 = *(const float4*)&BsB[kk][u * 4];
            float av[8] = {a0.x, a0.y, a0.z, a0.w, a1.x, a1.y, a1.z, a1.w};
            float bv_[8] = {b0.x, b0.y, b0.z, b0.w, b1.x, b1.y, b1.z, b1.w};
#pragma unroll
            for (int i = 0; i < 8; ++i)
#pragma unroll
                for (int j = 0; j < 8; ++j) acc[i][j] += av[i] * bv_[j];
        }
    }
#pragma unroll
    for (int i = 0; i < 8; ++i) {
        int ql = q0 + mg + i;
        if (ql < Lg) {
            float* pp = LG + ((size_t)h * NPOS + posbase + ql) * JS + n0 + jg;
            *(float4*)pp       = make_float4(acc[i][0], acc[i][1], acc[i][2], acc[i][3]);
            *(float4*)(pp + 4) = make_float4(acc[i][4], acc[i][5], acc[i][6], acc[i][7]);
        }
    }
}

// ---------------------------------------------------------------------------
// K3b: PV slab GEMM, ALL 4 heads per block (LG read exactly once).
// Block: 32 pos x 256 ch; j-range = ks*192..+192 within slab.
// mpart[ks][pos][ch] += softmax_h(LG[:,pos,j]) . V
// ---------------------------------------------------------------------------
__global__ __launch_bounds__(256) void k3b_pv(
    const float* __restrict__ LG, const float* __restrict__ hV,
    float* __restrict__ mpart, int j0, int first)
{
    __shared__ float Asm[4][16][34];   // [h][jj][pos]  alpha
    __shared__ float Bsv[16][264];     // [jj][ch]      V
    int t = threadIdx.x;
    int m0 = blockIdx.x * 32;          // global pos tile
    int ks = blockIdx.y;
    int jbase = ks * 192;

    float acc[2][16];
#pragma unroll
    for (int i = 0; i < 2; ++i)
#pragma unroll
        for (int j = 0; j < 16; ++j) acc[i][j] = 0.f;
    int pos2 = (t & 15) * 2;
    int ch16 = (t >> 4) * 16;
    int hch  = ch16 >> 6;
    int sj = t & 15, sp = t >> 4;

    for (int kc = 0; kc < 192; kc += 16) {
        __syncthreads();
        // stage V: 1024 float4 slots, 4 per thread
#pragma unroll
        for (int i = 0; i < 4; ++i) {
            int s = t + i * 256;
            int jj = s >> 6, c4 = (s & 63) * 4;
            int h = c4 >> 6, d = c4 & 63;
            int jglob = j0 + jbase + kc + jj;
            float4 x = make_float4(0.f, 0.f, 0.f, 0.f);
            if (jglob < NPOS)
                x = *(const float4*)(hV + ((size_t)h * NPOS + jglob) * 64 + d);
            *(float4*)&Bsv[jj][c4] = x;
        }
        // stage alpha: 32 pos x 16 j = 512 pairs, 2 per thread; softmax over heads
#pragma unroll
        for (int i = 0; i < 2; ++i) {
            int posl = sp + 16 * i;
            int pos = m0 + posl;
            int jglob = j0 + jbase + kc + sj;
            float v0 = 0.f, v1 = 0.f, v2 = 0.f, v3 = 0.f;
            if (pos < NPOS) {
                size_t base = (size_t)pos * JS + jbase + kc + sj;
                v0 = LG[base];
                v1 = LG[(size_t)NPOS * JS + base];
                v2 = LG[(size_t)2 * NPOS * JS + base];
                v3 = LG[(size_t)3 * NPOS * JS + base];
            }
            float mx = fmaxf(fmaxf(v0, v1), fmaxf(v2, v3));
            float e0 = __expf(v0 - mx), e1 = __expf(v1 - mx);
            float e2 = __expf(v2 - mx), e3 = __expf(v3 - mx);
            float inv = 1.0f / (e0 + e1 + e2 + e3);
            bool ok = (pos < NPOS) && (jglob < NPOS);
            float z = ok ? inv : 0.f;
            Asm[0][sj][posl] = e0 * z;
            Asm[1][sj][posl] = e1 * z;
            Asm[2][sj][posl] = e2 * z;
            Asm[3][sj][posl] = e3 * z;
        }
        __syncthreads();
#pragma unroll
        for (int kk = 0; kk < 16; ++kk) {
            float2 a = *(const float2*)&Asm[hch][kk][pos2];
            float4 b0 = *(const float4*)&Bsv[kk][ch16 + 0];
            float4 b1 = *(const float4*)&Bsv[kk][ch16 + 4];
            float4 b2 = *(const float4*)&Bsv[kk][ch16 + 8];
            float4 b3 = *(const float4*)&Bsv[kk][ch16 + 12];
            float bv_[16] = {b0.x, b0.y, b0.z, b0.w, b1.x, b1.y, b1.z, b1.w,
                             b2.x, b2.y, b2.z, b2.w, b3.x, b3.y, b3.z, b3.w};
#pragma unroll
            for (int j = 0; j < 16; ++j) {
                acc[0][j] += a.x * bv_[j];
                acc[1][j] += a.y * bv_[j];
            }
        }
    }
#pragma unroll
    for (int i = 0; i < 2; ++i) {
        int pos = m0 + pos2 + i;
        if (pos < NPOS) {
            float* pp = mpart + ((size_t)ks * NPOS + pos) * OUTF + ch16;
#pragma unroll
            for (int c = 0; c < 16; c += 4) {
                float4 prev = first ? make_float4(0.f, 0.f, 0.f, 0.f)
                                    : *(const float4*)(pp + c);
                *(float4*)(pp + c) = make_float4(prev.x + acc[i][c + 0],
                                                 prev.y + acc[i][c + 1],
                                                 prev.z + acc[i][c + 2],
                                                 prev.w + acc[i][c + 3]);
            }
        }
    }
}

// ---------------------------------------------------------------------------
// E1: m = mpart0+mpart1; relu; ln1; write concat buffer [H | ln1(relu(m))]
// ---------------------------------------------------------------------------
__global__ __launch_bounds__(256) void e1_relu_ln(
    const float* __restrict__ mpart, const float* __restrict__ Hb,
    const float* __restrict__ g1, const float* __restrict__ b1,
    float* __restrict__ cc)
{
    int w = threadIdx.x >> 6, lane = threadIdx.x & 63;
    int row = blockIdx.x * 4 + w;
    int c = lane * 4;
    float4 x0 = *(const float4*)(mpart + (size_t)row * OUTF + c);
    float4 x1 = *(const float4*)(mpart + (size_t)NPOS * OUTF + (size_t)row * OUTF + c);
    float x[4] = { fmaxf(x0.x + x1.x, 0.f), fmaxf(x0.y + x1.y, 0.f),
                   fmaxf(x0.z + x1.z, 0.f), fmaxf(x0.w + x1.w, 0.f) };
    float s = x[0] + x[1] + x[2] + x[3];
#pragma unroll
    for (int m = 32; m > 0; m >>= 1) s += __shfl_xor(s, m, 64);
    float mu = s * (1.0f / 256.0f);
    float vs = 0.f;
#pragma unroll
    for (int i = 0; i < 4; ++i) { float d = x[i] - mu; vs += d * d; }
#pragma unroll
    for (int m = 32; m > 0; m >>= 1) vs += __shfl_xor(vs, m, 64);
    float rs = rsqrtf(vs * (1.0f / 256.0f) + 1e-5f);
    float4 y;
    y.x = (x[0] - mu) * rs * g1[c + 0] + b1[c + 0];
    y.y = (x[1] - mu) * rs * g1[c + 1] + b1[c + 1];
    y.z = (x[2] - mu) * rs * g1[c + 2] + b1[c + 2];
    y.w = (x[3] - mu) * rs * g1[c + 3] + b1[c + 3];
    *(float4*)(cc + (size_t)row * INF + OUTF + c) = y;
    float4 hh = *(const float4*)(Hb + (size_t)row * OUTF + c);
    *(float4*)(cc + (size_t)row * INF + c) = hh;
}

// ---------------------------------------------------------------------------
// E2: beta = sigmoid(cc @ Wbeta + bbeta); out = beta*m1 + (1-beta)*H
// ---------------------------------------------------------------------------
__global__ __launch_bounds__(256) void e2_beta(
    const float* __restrict__ cc, const float* __restrict__ Wb,
    const float* __restrict__ bb, float* __restrict__ outb)
{
    __shared__ float AT[16][68];
    __shared__ float Bs[16][132];
    int t = threadIdx.x;
    int n0 = blockIdx.x * 128;
    int m0 = blockIdx.y * 64;
    float acc[4][8];
#pragma unroll
    for (int i = 0; i < 4; ++i)
#pragma unroll
        for (int j = 0; j < 8; ++j) acc[i][j] = 0.f;
    int mg = (t >> 4) * 4, jg = (t & 15) * 8;
    int am = t & 63, ak = (t >> 6) * 4;
    int bkk = t >> 4, bn = (t & 15) * 8;
    for (int k0 = 0; k0 < INF; k0 += 16) {
        __syncthreads();
        {
            int row = m0 + am;
            float4 v = make_float4(0.f, 0.f, 0.f, 0.f);
            if (row < NPOS) v = *(const float4*)(cc + (size_t)row * INF + k0 + ak);
            AT[ak + 0][am] = v.x; AT[ak + 1][am] = v.y;
            AT[ak + 2][am] = v.z; AT[ak + 3][am] = v.w;
        }
        {
            const float* p = Wb + (size_t)(k0 + bkk) * OUTF + n0 + bn;
            float4 u0 = *(const float4*)p;
            float4 u1 = *(const float4*)(p + 4);
            *(float4*)&Bs[bkk][bn]     = u0;
            *(float4*)&Bs[bkk][bn + 4] = u1;
        }
        __syncthreads();
#pragma unroll
        for (int kk = 0; kk < 16; ++kk) {
            float4 a  = *(const float4*)&AT[kk][mg];
            float4 b0 = *(const float4*)&Bs[kk][jg];
            float4 b1 = *(const float4*)&Bs[kk][jg + 4];
            float av[4] = {a.x, a.y, a.z, a.w};
            float bv_[8] = {b0.x, b0.y, b0.z, b0.w, b1.x, b1.y, b1.z, b1.w};
#pragma unroll
            for (int i = 0; i < 4; ++i)
#pragma unroll
                for (int j = 0; j < 8; ++j) acc[i][j] += av[i] * bv_[j];
        }
    }
#pragma unroll
    for (int i = 0; i < 4; ++i) {
        int row = m0 + mg + i;
        if (row < NPOS) {
#pragma unroll
            for (int j = 0; j < 8; ++j) {
                int n = n0 + jg + j;
                float x = acc[i][j] + bb[n];
                float sg = 1.0f / (1.0f + __expf(-x));
                float m1v = cc[(size_t)row * INF + OUTF + n];
                float Hv  = cc[(size_t)row * INF + n];
                outb[(size_t)row * OUTF + n] = sg * m1v + (1.0f - sg) * Hv;
            }
        }
    }
}

// ---------------------------------------------------------------------------
// E3: t = out @ w1 + b1 ; ln2(eps=1e-6) ; tanh -> h2.
// ---------------------------------------------------------------------------
__global__ __launch_bounds__(256) void e3_w1_ln2(
    const float* __restrict__ outb, const float* __restrict__ w1,
    const float* __restrict__ b1v, const float* __restrict__ g2,
    const float* __restrict__ b2v, float* __restrict__ h2o)
{
    __shared__ float As[16][260];
    __shared__ float Bs[16][260];
    __shared__ float red[16][17];
    int t = threadIdx.x;
    int m0 = blockIdx.x * 16;
    {
        int rr = t >> 4, c4 = (t & 15) * 4;
        int row = m0 + rr;
#pragma unroll
        for (int i = 0; i < 4; ++i) {
            int c = c4 + i * 64;
            float4 x = make_float4(0.f, 0.f, 0.f, 0.f);
            if (row < NPOS) x = *(const float4*)(outb + (size_t)row * OUTF + c);
            *(float4*)&As[rr][c] = x;
        }
    }
    int q = t & 15, dg = (t >> 4) * 16;
    float acc[16];
#pragma unroll
    for (int i = 0; i < 16; ++i) acc[i] = 0.f;
    for (int k0 = 0; k0 < 256; k0 += 16) {
        __syncthreads();
        {
            int kk = t >> 4, n16 = (t & 15) * 16;
#pragma unroll
            for (int i = 0; i < 4; ++i) {
                float4 x = *(const float4*)(w1 + (size_t)(k0 + kk) * OUTF + n16 + i * 4);
                *(float4*)&Bs[kk][n16 + i * 4] = x;
            }
        }
        __syncthreads();
#pragma unroll
        for (int kk = 0; kk < 16; ++kk) {
            float a = As[q][k0 + kk];
#pragma unroll
            for (int i = 0; i < 16; i += 4) {
                float4 b = *(const float4*)&Bs[kk][dg + i];
                acc[i + 0] += a * b.x; acc[i + 1] += a * b.y;
                acc[i + 2] += a * b.z; acc[i + 3] += a * b.w;
            }
        }
    }
    float x[16];
#pragma unroll
    for (int i = 0; i < 16; ++i) x[i] = acc[i] + b1v[dg + i];
    float ps = 0.f;
#pragma unroll
    for (int i = 0; i < 16; ++i) ps += x[i];
    __syncthreads();
    red[t >> 4][q] = ps;
    __syncthreads();
    float s = 0.f;
#pragma unroll
    for (int i = 0; i < 16; ++i) s += red[i][q];
    float mu = s * (1.0f / 256.0f);
    float pv = 0.f;
#pragma unroll
    for (int i = 0; i < 16; ++i) { float d = x[i] - mu; pv += d * d; }
    __syncthreads();
    red[t >> 4][q] = pv;
    __syncthreads();
    float v = 0.f;
#pragma unroll
    for (int i = 0; i < 16; ++i) v += red[i][q];
    float rs = rsqrtf(v * (1.0f / 256.0f) + 1e-6f);
    int row = m0 + q;
    if (row < NPOS) {
#pragma unroll
        for (int i = 0; i < 16; ++i) {
            int n = dg + i;
            h2o[(size_t)row * OUTF + n] = tanhf((x[i] - mu) * rs * g2[n] + b2v[n]);
        }
    }
}

// ---------------------------------------------------------------------------
// E4: final = h2 @ w2  (no bias) -> d_out
// ---------------------------------------------------------------------------
__global__ __launch_bounds__(256) void e4_final(
    const float* __restrict__ h2in, const float* __restrict__ w2,
    float* __restrict__ outp)
{
    __shared__ float AT[16][68];
    __shared__ float Bs[16][132];
    int t = threadIdx.x;
    int n0 = blockIdx.x * 128;
    int m0 = blockIdx.y * 64;
    float acc[4][8];
#pragma unroll
    for (int i = 0; i < 4; ++i)
#pragma unroll
        for (int j = 0; j < 8; ++j) acc[i][j] = 0.f;
    int mg = (t >> 4) * 4, jg = (t & 15) * 8;
    int am = t & 63, ak = (t >> 6) * 4;
    int bkk = t >> 4, bn = (t & 15) * 8;
    for (int k0 = 0; k0 < 256; k0 += 16) {
        __syncthreads();
        {
            int row = m0 + am;
            float4 v = make_float4(0.f, 0.f, 0.f, 0.f);
            if (row < NPOS) v = *(const float4*)(h2in + (size_t)row * OUTF + k0 + ak);
            AT[ak + 0][am] = v.x; AT[ak + 1][am] = v.y;
            AT[ak + 2][am] = v.z; AT[ak + 3][am] = v.w;
        }
        {
            const float* p = w2 + (size_t)(k0 + bkk) * OUTF + n0 + bn;
            float4 u0 = *(const float4*)p;
            float4 u1 = *(const float4*)(p + 4);
            *(float4*)&Bs[bkk][bn]     = u0;
            *(float4*)&Bs[bkk][bn + 4] = u1;
        }
        __syncthreads();
#pragma unroll
        for (int kk = 0; kk < 16; ++kk) {
            float4 a  = *(const float4*)&AT[kk][mg];
            float4 b0 = *(const float4*)&Bs[kk][jg];
            float4 b1 = *(const float4*)&Bs[kk][jg + 4];
            float av[4] = {a.x, a.y, a.z, a.w};
            float bv_[8] = {b0.x, b0.y, b0.z, b0.w, b1.x, b1.y, b1.z, b1.w};
#pragma unroll
            for (int i = 0; i < 4; ++i)
#pragma unroll
                for (int j = 0; j < 8; ++j) acc[i][j] += av[i] * bv_[j];
        }
    }
#pragma unroll
    for (int i = 0; i < 4; ++i) {
        int row = m0 + mg + i;
        if (row < NPOS) {
#pragma unroll
            for (int j = 0; j < 8; ++j) {
                outp[(size_t)row * OUTF + n0 + jg + j] = acc[i][j];
            }
        }
    }
}

// ---------------------------------------------------------------------------
extern "C" void kernel_launch(void* const* d_in, const int* in_sizes, int n_in,
                              void* d_out, int out_size, void* d_ws, size_t ws_size,
                              hipStream_t stream)
{
    const float* feature = (const float*)d_in[0];
    const float* adj   = (const float*)d_in[1];
    const float* r     = (const float*)d_in[2];
    const float* Wq    = (const float*)d_in[3];
    const float* bq    = (const float*)d_in[4];
    const float* Wk    = (const float*)d_in[5];
    const float* bk    = (const float*)d_in[6];
    const float* Wv    = (const float*)d_in[7];
    const float* bv    = (const float*)d_in[8];
    const float* Ww    = (const float*)d_in[9];
    const float* bw    = (const float*)d_in[10];
    const float* Wr    = (const float*)d_in[11];
    const float* br    = (const float*)d_in[12];
    const float* Wbeta = (const float*)d_in[13];
    const float* bbeta = (const float*)d_in[14];
    const float* ln1g  = (const float*)d_in[15];
    const float* ln1b  = (const float*)d_in[16];
    const float* w1    = (const float*)d_in[17];
    const float* b1    = (const float*)d_in[18];
    const float* ln2g  = (const float*)d_in[19];
    const float* ln2b  = (const float*)d_in[20];
    const float* w2    = (const float*)d_in[21];
    const int*   flag  = (const int*)d_in[22];
    float* out = (float*)d_out;

    // --- workspace layout (liveness-aliased) ---
    // [0, 30105600)        : LG (4*4900*384*4)
    // [30130176, 35147776) : hQ ; [35147776, 40165376): hK ; cc aliases both
    // [40165376, 45182976) : hV ; outb aliases
    // [45182976, 50200576) : Hb ; hh2 aliases
    // [50200576, 60243968) : BcP0 (512*4904*4)
    // [60243968, 70287360) : BcP1
    // [70287360, 80322560) : mpart (2*4900*256*4)
    // [80322560, 80325632) : S
    char* ws = (char*)d_ws;
    float* LG    = (float*)(ws + 0);
    float* hQ    = (float*)(ws + 30130176);
    float* hK    = (float*)(ws + 35147776);
    float* cc    = (float*)(ws + 30130176);
    float* hV    = (float*)(ws + 40165376);
    float* outb  = (float*)(ws + 40165376);
    float* Hb    = (float*)(ws + 45182976);
    float* hh2   = (float*)(ws + 45182976);
    float* BcP0  = (float*)(ws + 50200576);
    float* BcP1  = (float*)(ws + 60243968);
    float* mpart = (float*)(ws + 70287360);
    float* S     = (float*)(ws + 80322560);

    k0_rp<<<1, 256, 0, stream>>>(r, Wr, br, flag, S);
    k1_proj<<<dim3(8, 77), 256, 0, stream>>>(feature, Wq, bq, Wk, bk, Wv, bv, Ww, bw,
                                             hQ, hK, hV, Hb);
    k2_pgemm<<<dim3(77, 2, 2), 256, 0, stream>>>(hK, adj, S, BcP0, BcP1);
    for (int s = 0; s < NSLAB; ++s) {
        int j0 = s * JS;
        k3a_logits<<<dim3(3, 156), 256, 0, stream>>>(hQ, S, BcP0, BcP1, LG, j0);
        k3b_pv<<<dim3(154, 2), 256, 0, stream>>>(LG, hV, mpart, j0, s == 0 ? 1 : 0);
    }
    e1_relu_ln<<<1225, 256, 0, stream>>>(mpart, Hb, ln1g, ln1b, cc);
    e2_beta<<<dim3(2, 77), 256, 0, stream>>>(cc, Wbeta, bbeta, outb);
    e3_w1_ln2<<<307, 256, 0, stream>>>(outb, w1, b1, ln2g, ln2b, hh2);
    e4_final<<<dim3(2, 77), 256, 0, stream>>>(hh2, w2, out);
}

// Round 4
// 1855.161 us; speedup vs baseline: 1.3173x; 1.3173x over previous
//
#include <hip/hip_runtime.h>
#include <hip/hip_bf16.h>
#include <math.h>

#define NPOS 4900
#define NG1  708
#define NG2  4192
#define INF  512
#define OUTF 256
#define JPAD 4904       // padded j-stride for BcP planes (mult of 8, >= 4900)
#define JS   384        // logits slab width
#define NSLAB 13        // ceil(4900/384)

// ---------------------------------------------------------------------------
// K0: rp = r @ Wr + br  (4x256); store S[0]=rp[ridx], S[1]=rp[2], S[2]=rp[3]
// ---------------------------------------------------------------------------
__global__ __launch_bounds__(256) void k0_rp(
    const float* __restrict__ r, const float* __restrict__ Wr,
    const float* __restrict__ br, const int* __restrict__ flagp,
    float* __restrict__ S)
{
    __shared__ float rsh[1024];
    int t = threadIdx.x;
    for (int i = t; i < 1024; i += 256) rsh[i] = r[i];
    __syncthreads();
    float a0 = 0.f, a1 = 0.f, a2 = 0.f, a3 = 0.f;
    for (int c = 0; c < 256; ++c) {
        float w = Wr[c * 256 + t];
        a0 += rsh[c] * w;
        a1 += rsh[256 + c] * w;
        a2 += rsh[512 + c] * w;
        a3 += rsh[768 + c] * w;
    }
    float b = br[t];
    a0 += b; a1 += b; a2 += b; a3 += b;
    int ridx = (flagp[0] != 0) ? 1 : 0;
    S[t]         = ridx ? a1 : a0;
    S[256 + t]   = a2;
    S[512 + t]   = a3;
}

// ---------------------------------------------------------------------------
// K1: fused projections hQ/hK/hV/H = feature @ {Wq,Wk,Wv,Ww} + bias
// ---------------------------------------------------------------------------
__global__ __launch_bounds__(256) void k1_proj(
    const float* __restrict__ feat,
    const float* __restrict__ Wq, const float* __restrict__ bq,
    const float* __restrict__ Wk, const float* __restrict__ bk,
    const float* __restrict__ Wv, const float* __restrict__ bv,
    const float* __restrict__ Ww, const float* __restrict__ bw,
    float* __restrict__ hQ, float* __restrict__ hK,
    float* __restrict__ hV, float* __restrict__ Hb)
{
    __shared__ float AT[16][68];    // [k][m]
    __shared__ float Bs[16][132];   // [k][n]
    int t = threadIdx.x;
    int mat = blockIdx.x >> 1;
    int n0  = (blockIdx.x & 1) * 128;
    int m0  = blockIdx.y * 64;
    const float* W; const float* bias; float* dst;
    switch (mat) {
        case 0:  W = Wq; bias = bq; dst = hQ; break;
        case 1:  W = Wk; bias = bk; dst = hK; break;
        case 2:  W = Wv; bias = bv; dst = hV; break;
        default: W = Ww; bias = bw; dst = Hb; break;
    }
    float acc[4][8];
#pragma unroll
    for (int i = 0; i < 4; ++i)
#pragma unroll
        for (int j = 0; j < 8; ++j) acc[i][j] = 0.f;
    int mg = (t >> 4) * 4, jg = (t & 15) * 8;
    int am = t & 63, ak = (t >> 6) * 4;
    int bkk = t >> 4, bn = (t & 15) * 8;
    for (int k0 = 0; k0 < INF; k0 += 16) {
        __syncthreads();
        {
            int row = m0 + am;
            float4 v = make_float4(0.f, 0.f, 0.f, 0.f);
            if (row < NPOS) v = *(const float4*)(feat + (size_t)row * INF + k0 + ak);
            AT[ak + 0][am] = v.x; AT[ak + 1][am] = v.y;
            AT[ak + 2][am] = v.z; AT[ak + 3][am] = v.w;
        }
        {
            const float* p = W + (size_t)(k0 + bkk) * OUTF + n0 + bn;
            float4 u0 = *(const float4*)p;
            float4 u1 = *(const float4*)(p + 4);
            *(float4*)&Bs[bkk][bn]     = u0;
            *(float4*)&Bs[bkk][bn + 4] = u1;
        }
        __syncthreads();
#pragma unroll
        for (int kk = 0; kk < 16; ++kk) {
            float4 a  = *(const float4*)&AT[kk][mg];
            float4 b0 = *(const float4*)&Bs[kk][jg];
            float4 b1 = *(const float4*)&Bs[kk][jg + 4];
            float av[4] = {a.x, a.y, a.z, a.w};
            float bv_[8] = {b0.x, b0.y, b0.z, b0.w, b1.x, b1.y, b1.z, b1.w};
#pragma unroll
            for (int i = 0; i < 4; ++i)
#pragma unroll
                for (int j = 0; j < 8; ++j) acc[i][j] += av[i] * bv_[j];
        }
    }
#pragma unroll
    for (int i = 0; i < 4; ++i) {
        int row = m0 + mg + i;
        if (row < NPOS) {
#pragma unroll
            for (int j = 0; j < 8; ++j) {
                int n = n0 + jg + j;
                dst[(size_t)row * OUTF + n] = acc[i][j] + bias[n];
            }
        }
    }
}

// ---------------------------------------------------------------------------
// K2 v3: BcP[part][g*256 + h*64 + dd][j] = sum_k A[dd][k] * adj[rowoff+k][j]
//   A[dd][k] = hKpart[(h*L+k)*64+dd] * 0.5 * S[g+part][(k&3)*64+dd]
// Tile M=64 (one h), N=64, BK=16.  Grid (77 j, 8 gh, 2 part) = 1232 blocks.
// 4x4 microtile per thread (16 acc). Conflict-free LDS (broadcast reads).
// ---------------------------------------------------------------------------
__global__ __launch_bounds__(256) void k2_pgemm(
    const float* __restrict__ hK, const float* __restrict__ adj,
    const float* __restrict__ S,
    float* __restrict__ BcP0, float* __restrict__ BcP1)
{
    __shared__ float As[16][68];    // [kk][dd]
    __shared__ float Bs[16][68];    // [kk][j]
    int t = threadIdx.x;
    int j0 = blockIdx.x * 64;
    int gh = blockIdx.y;
    int g = gh >> 2, h = gh & 3;
    int part = blockIdx.z;
    int L = part ? NG2 : NG1;
    const float* kflat = hK + (part ? (size_t)NG1 * OUTF : 0);
    const float* sv = S + (g + part) * 256;
    int rowoff = part ? NG1 : 0;
    float* dst = (part ? BcP1 : BcP0) + (size_t)(g * 256 + h * 64) * JPAD;

    float acc[4][4];
#pragma unroll
    for (int i = 0; i < 4; ++i)
#pragma unroll
        for (int j = 0; j < 4; ++j) acc[i][j] = 0.f;

    int mi = t >> 4, ni = t & 15;        // 16x16 thread grid, 4x4 microtile
    int kk = t >> 4, d4 = (t & 15) * 4;  // staging coords
    int Ksteps = (L + 15) >> 4;

    for (int ks = 0; ks < Ksteps; ++ks) {
        int kv = ks * 16 + kk;
        // prefetch to registers before barrier
        float4 av = make_float4(0.f, 0.f, 0.f, 0.f);
        float4 bvv = make_float4(0.f, 0.f, 0.f, 0.f);
        if (kv < L) {
            float4 x  = *(const float4*)(kflat + ((size_t)(h * L + kv)) * 64 + d4);
            float4 s4 = *(const float4*)(sv + (kv & 3) * 64 + d4);
            av = make_float4(0.5f * x.x * s4.x, 0.5f * x.y * s4.y,
                             0.5f * x.z * s4.z, 0.5f * x.w * s4.w);
            int col = j0 + d4;
            const float* p = adj + (size_t)(rowoff + kv) * NPOS + col;
            if (col + 3 < NPOS) bvv = *(const float4*)p;
            else {
                bvv.x = (col + 0 < NPOS) ? p[0] : 0.f;
                bvv.y = (col + 1 < NPOS) ? p[1] : 0.f;
                bvv.z = (col + 2 < NPOS) ? p[2] : 0.f;
                bvv.w = (col + 3 < NPOS) ? p[3] : 0.f;
            }
        }
        __syncthreads();
        *(float4*)&As[kk][d4] = av;
        *(float4*)&Bs[kk][d4] = bvv;
        __syncthreads();
#pragma unroll
        for (int k2i = 0; k2i < 16; ++k2i) {
            float4 a = *(const float4*)&As[k2i][mi * 4];
            float4 b = *(const float4*)&Bs[k2i][ni * 4];
            float aa[4] = {a.x, a.y, a.z, a.w};
            float bb[4] = {b.x, b.y, b.z, b.w};
#pragma unroll
            for (int i = 0; i < 4; ++i)
#pragma unroll
                for (int j = 0; j < 4; ++j) acc[i][j] += aa[i] * bb[j];
        }
    }
    int colb = j0 + ni * 4;
#pragma unroll
    for (int i = 0; i < 4; ++i) {
        float* drow = dst + (size_t)(mi * 4 + i) * JPAD + colb;
        if (colb + 3 < NPOS) {
            *(float4*)drow = make_float4(acc[i][0], acc[i][1], acc[i][2], acc[i][3]);
        } else {
#pragma unroll
            for (int j = 0; j < 4; ++j)
                if (colb + j < NPOS) drow[j] = acc[i][j];
        }
    }
}

// ---------------------------------------------------------------------------
// K3a: logits slab GEMM.  LG[h][pos][jloc] = Q~[h,pos][0:128] . BcP[:, j0+jloc]
// K<64 from BcP0, K>=64 from BcP1.  Tile M=128, N=128, K=128.
// ---------------------------------------------------------------------------
__global__ __launch_bounds__(256) void k3a_logits(
    const float* __restrict__ hQ, const float* __restrict__ S,
    const float* __restrict__ BcP0, const float* __restrict__ BcP1,
    float* __restrict__ LG, int j0)
{
    __shared__ float As[16][132];    // [kk][m]
    __shared__ float BsA[16][68];    // cols jg..jg+3
    __shared__ float BsB[16][68];    // cols jg+4..jg+7
    int t = threadIdx.x;
    int n0 = blockIdx.x * 128;       // 0,128,256 within slab
    int y = blockIdx.y;              // 156 = 4h * 39
    int h = y / 39, rr = y % 39;
    int g, tile;
    if (rr < 6) { g = 0; tile = rr; } else { g = 1; tile = rr - 6; }
    int Lg = g ? NG2 : NG1;
    int vbase = g ? NG1 * OUTF : 0;
    int posbase = g ? NG1 : 0;
    int q0 = tile * 128;

    float acc[8][8];
#pragma unroll
    for (int i = 0; i < 8; ++i)
#pragma unroll
        for (int j = 0; j < 8; ++j) acc[i][j] = 0.f;
    int mg = (t >> 4) * 8, jg = (t & 15) * 8;
    int u = t & 15;
    int bkk = t >> 4;

    for (int k0 = 0; k0 < 128; k0 += 16) {
        int p = k0 >> 6;
        __syncthreads();
        // stage A (Q scaled): 512 float4 slots, 2 per thread
#pragma unroll
        for (int i = 0; i < 2; ++i) {
            int s = t + i * 256;
            int m = s >> 2, kq = (s & 3) * 4;
            int d = (k0 & 63) + kq;
            int ql = q0 + m;
            float4 v = make_float4(0.f, 0.f, 0.f, 0.f);
            if (ql < Lg) {
                float4 qv = *(const float4*)(hQ + vbase + (size_t)(h * Lg + ql) * 64 + d);
                float4 sv = *(const float4*)(S + (g + p) * 256 + (ql & 3) * 64 + d);
                v = make_float4(qv.x * sv.x, qv.y * sv.y, qv.z * sv.z, qv.w * sv.w);
            }
            As[kq + 0][m] = v.x; As[kq + 1][m] = v.y;
            As[kq + 2][m] = v.z; As[kq + 3][m] = v.w;
        }
        // stage B from part plane (de-interleaved)
        {
            const float* plane = p ? BcP1 : BcP0;
            int row = (g * 4 + h) * 64 + (k0 & 63) + bkk;
            int col = j0 + n0 + u * 8;
            float4 c0 = make_float4(0.f, 0.f, 0.f, 0.f);
            float4 c1 = make_float4(0.f, 0.f, 0.f, 0.f);
            if (col + 7 < JPAD) {
                const float* pp = plane + (size_t)row * JPAD + col;
                c0 = *(const float4*)pp;
                c1 = *(const float4*)(pp + 4);
            }
            *(float4*)&BsA[bkk][u * 4] = c0;
            *(float4*)&BsB[bkk][u * 4] = c1;
        }
        __syncthreads();
#pragma unroll
        for (int kk = 0; kk < 16; ++kk) {
            float4 a0 = *(const float4*)&As[kk][mg];
            float4 a1 = *(const float4*)&As[kk][mg + 4];
            float4 b0 = *(const float4*)&BsA[kk][u * 4];
            float4 b1 = *(const float4*)&BsB[kk][u * 4];
            float av[8] = {a0.x, a0.y, a0.z, a0.w, a1.x, a1.y, a1.z, a1.w};
            float bv_[8] = {b0.x, b0.y, b0.z, b0.w, b1.x, b1.y, b1.z, b1.w};
#pragma unroll
            for (int i = 0; i < 8; ++i)
#pragma unroll
                for (int j = 0; j < 8; ++j) acc[i][j] += av[i] * bv_[j];
        }
    }
#pragma unroll
    for (int i = 0; i < 8; ++i) {
        int ql = q0 + mg + i;
        if (ql < Lg) {
            float* pp = LG + ((size_t)h * NPOS + posbase + ql) * JS + n0 + jg;
            *(float4*)pp       = make_float4(acc[i][0], acc[i][1], acc[i][2], acc[i][3]);
            *(float4*)(pp + 4) = make_float4(acc[i][4], acc[i][5], acc[i][6], acc[i][7]);
        }
    }
}

// ---------------------------------------------------------------------------
// K3b: PV slab GEMM, ALL 4 heads per block (LG read exactly once).
// Block: 32 pos x 256 ch; j-range = ks*192..+192 within slab.
// mpart[ks][pos][ch] += softmax_h(LG[:,pos,j]) . V
// ---------------------------------------------------------------------------
__global__ __launch_bounds__(256) void k3b_pv(
    const float* __restrict__ LG, const float* __restrict__ hV,
    float* __restrict__ mpart, int j0, int first)
{
    __shared__ float Asm[4][16][34];   // [h][jj][pos]  alpha
    __shared__ float Bsv[16][264];     // [jj][ch]      V
    int t = threadIdx.x;
    int m0 = blockIdx.x * 32;          // global pos tile
    int ks = blockIdx.y;
    int jbase = ks * 192;

    float acc[2][16];
#pragma unroll
    for (int i = 0; i < 2; ++i)
#pragma unroll
        for (int j = 0; j < 16; ++j) acc[i][j] = 0.f;
    int pos2 = (t & 15) * 2;
    int ch16 = (t >> 4) * 16;
    int hch  = ch16 >> 6;
    int sj = t & 15, sp = t >> 4;

    for (int kc = 0; kc < 192; kc += 16) {
        __syncthreads();
        // stage V: 1024 float4 slots, 4 per thread
#pragma unroll
        for (int i = 0; i < 4; ++i) {
            int s = t + i * 256;
            int jj = s >> 6, c4 = (s & 63) * 4;
            int h = c4 >> 6, d = c4 & 63;
            int jglob = j0 + jbase + kc + jj;
            float4 x = make_float4(0.f, 0.f, 0.f, 0.f);
            if (jglob < NPOS)
                x = *(const float4*)(hV + ((size_t)h * NPOS + jglob) * 64 + d);
            *(float4*)&Bsv[jj][c4] = x;
        }
        // stage alpha: 32 pos x 16 j = 512 pairs, 2 per thread; softmax over heads
#pragma unroll
        for (int i = 0; i < 2; ++i) {
            int posl = sp + 16 * i;
            int pos = m0 + posl;
            int jglob = j0 + jbase + kc + sj;
            float v0 = 0.f, v1 = 0.f, v2 = 0.f, v3 = 0.f;
            if (pos < NPOS) {
                size_t base = (size_t)pos * JS + jbase + kc + sj;
                v0 = LG[base];
                v1 = LG[(size_t)NPOS * JS + base];
                v2 = LG[(size_t)2 * NPOS * JS + base];
                v3 = LG[(size_t)3 * NPOS * JS + base];
            }
            float mx = fmaxf(fmaxf(v0, v1), fmaxf(v2, v3));
            float e0 = __expf(v0 - mx), e1 = __expf(v1 - mx);
            float e2 = __expf(v2 - mx), e3 = __expf(v3 - mx);
            float inv = 1.0f / (e0 + e1 + e2 + e3);
            bool ok = (pos < NPOS) && (jglob < NPOS);
            float z = ok ? inv : 0.f;
            Asm[0][sj][posl] = e0 * z;
            Asm[1][sj][posl] = e1 * z;
            Asm[2][sj][posl] = e2 * z;
            Asm[3][sj][posl] = e3 * z;
        }
        __syncthreads();
#pragma unroll
        for (int kk = 0; kk < 16; ++kk) {
            float2 a = *(const float2*)&Asm[hch][kk][pos2];
            float4 b0 = *(const float4*)&Bsv[kk][ch16 + 0];
            float4 b1 = *(const float4*)&Bsv[kk][ch16 + 4];
            float4 b2 = *(const float4*)&Bsv[kk][ch16 + 8];
            float4 b3 = *(const float4*)&Bsv[kk][ch16 + 12];
            float bv_[16] = {b0.x, b0.y, b0.z, b0.w, b1.x, b1.y, b1.z, b1.w,
                             b2.x, b2.y, b2.z, b2.w, b3.x, b3.y, b3.z, b3.w};
#pragma unroll
            for (int j = 0; j < 16; ++j) {
                acc[0][j] += a.x * bv_[j];
                acc[1][j] += a.y * bv_[j];
            }
        }
    }
#pragma unroll
    for (int i = 0; i < 2; ++i) {
        int pos = m0 + pos2 + i;
        if (pos < NPOS) {
            float* pp = mpart + ((size_t)ks * NPOS + pos) * OUTF + ch16;
#pragma unroll
            for (int c = 0; c < 16; c += 4) {
                float4 prev = first ? make_float4(0.f, 0.f, 0.f, 0.f)
                                    : *(const float4*)(pp + c);
                *(float4*)(pp + c) = make_float4(prev.x + acc[i][c + 0],
                                                 prev.y + acc[i][c + 1],
                                                 prev.z + acc[i][c + 2],
                                                 prev.w + acc[i][c + 3]);
            }
        }
    }
}

// ---------------------------------------------------------------------------
// E1: m = mpart0+mpart1; relu; ln1; write concat buffer [H | ln1(relu(m))]
// ---------------------------------------------------------------------------
__global__ __launch_bounds__(256) void e1_relu_ln(
    const float* __restrict__ mpart, const float* __restrict__ Hb,
    const float* __restrict__ g1, const float* __restrict__ b1,
    float* __restrict__ cc)
{
    int w = threadIdx.x >> 6, lane = threadIdx.x & 63;
    int row = blockIdx.x * 4 + w;
    int c = lane * 4;
    float4 x0 = *(const float4*)(mpart + (size_t)row * OUTF + c);
    float4 x1 = *(const float4*)(mpart + (size_t)NPOS * OUTF + (size_t)row * OUTF + c);
    float x[4] = { fmaxf(x0.x + x1.x, 0.f), fmaxf(x0.y + x1.y, 0.f),
                   fmaxf(x0.z + x1.z, 0.f), fmaxf(x0.w + x1.w, 0.f) };
    float s = x[0] + x[1] + x[2] + x[3];
#pragma unroll
    for (int m = 32; m > 0; m >>= 1) s += __shfl_xor(s, m, 64);
    float mu = s * (1.0f / 256.0f);
    float vs = 0.f;
#pragma unroll
    for (int i = 0; i < 4; ++i) { float d = x[i] - mu; vs += d * d; }
#pragma unroll
    for (int m = 32; m > 0; m >>= 1) vs += __shfl_xor(vs, m, 64);
    float rs = rsqrtf(vs * (1.0f / 256.0f) + 1e-5f);
    float4 y;
    y.x = (x[0] - mu) * rs * g1[c + 0] + b1[c + 0];
    y.y = (x[1] - mu) * rs * g1[c + 1] + b1[c + 1];
    y.z = (x[2] - mu) * rs * g1[c + 2] + b1[c + 2];
    y.w = (x[3] - mu) * rs * g1[c + 3] + b1[c + 3];
    *(float4*)(cc + (size_t)row * INF + OUTF + c) = y;
    float4 hh = *(const float4*)(Hb + (size_t)row * OUTF + c);
    *(float4*)(cc + (size_t)row * INF + c) = hh;
}

// ---------------------------------------------------------------------------
// E2: beta = sigmoid(cc @ Wbeta + bbeta); out = beta*m1 + (1-beta)*H
// ---------------------------------------------------------------------------
__global__ __launch_bounds__(256) void e2_beta(
    const float* __restrict__ cc, const float* __restrict__ Wb,
    const float* __restrict__ bb, float* __restrict__ outb)
{
    __shared__ float AT[16][68];
    __shared__ float Bs[16][132];
    int t = threadIdx.x;
    int n0 = blockIdx.x * 128;
    int m0 = blockIdx.y * 64;
    float acc[4][8];
#pragma unroll
    for (int i = 0; i < 4; ++i)
#pragma unroll
        for (int j = 0; j < 8; ++j) acc[i][j] = 0.f;
    int mg = (t >> 4) * 4, jg = (t & 15) * 8;
    int am = t & 63, ak = (t >> 6) * 4;
    int bkk = t >> 4, bn = (t & 15) * 8;
    for (int k0 = 0; k0 < INF; k0 += 16) {
        __syncthreads();
        {
            int row = m0 + am;
            float4 v = make_float4(0.f, 0.f, 0.f, 0.f);
            if (row < NPOS) v = *(const float4*)(cc + (size_t)row * INF + k0 + ak);
            AT[ak + 0][am] = v.x; AT[ak + 1][am] = v.y;
            AT[ak + 2][am] = v.z; AT[ak + 3][am] = v.w;
        }
        {
            const float* p = Wb + (size_t)(k0 + bkk) * OUTF + n0 + bn;
            float4 u0 = *(const float4*)p;
            float4 u1 = *(const float4*)(p + 4);
            *(float4*)&Bs[bkk][bn]     = u0;
            *(float4*)&Bs[bkk][bn + 4] = u1;
        }
        __syncthreads();
#pragma unroll
        for (int kk = 0; kk < 16; ++kk) {
            float4 a  = *(const float4*)&AT[kk][mg];
            float4 b0 = *(const float4*)&Bs[kk][jg];
            float4 b1 = *(const float4*)&Bs[kk][jg + 4];
            float av[4] = {a.x, a.y, a.z, a.w};
            float bv_[8] = {b0.x, b0.y, b0.z, b0.w, b1.x, b1.y, b1.z, b1.w};
#pragma unroll
            for (int i = 0; i < 4; ++i)
#pragma unroll
                for (int j = 0; j < 8; ++j) acc[i][j] += av[i] * bv_[j];
        }
    }
#pragma unroll
    for (int i = 0; i < 4; ++i) {
        int row = m0 + mg + i;
        if (row < NPOS) {
#pragma unroll
            for (int j = 0; j < 8; ++j) {
                int n = n0 + jg + j;
                float x = acc[i][j] + bb[n];
                float sg = 1.0f / (1.0f + __expf(-x));
                float m1v = cc[(size_t)row * INF + OUTF + n];
                float Hv  = cc[(size_t)row * INF + n];
                outb[(size_t)row * OUTF + n] = sg * m1v + (1.0f - sg) * Hv;
            }
        }
    }
}

// ---------------------------------------------------------------------------
// E3: t = out @ w1 + b1 ; ln2(eps=1e-6) ; tanh -> h2.
// ---------------------------------------------------------------------------
__global__ __launch_bounds__(256) void e3_w1_ln2(
    const float* __restrict__ outb, const float* __restrict__ w1,
    const float* __restrict__ b1v, const float* __restrict__ g2,
    const float* __restrict__ b2v, float* __restrict__ h2o)
{
    __shared__ float As[16][260];
    __shared__ float Bs[16][260];
    __shared__ float red[16][17];
    int t = threadIdx.x;
    int m0 = blockIdx.x * 16;
    {
        int rr = t >> 4, c4 = (t & 15) * 4;
        int row = m0 + rr;
#pragma unroll
        for (int i = 0; i < 4; ++i) {
            int c = c4 + i * 64;
            float4 x = make_float4(0.f, 0.f, 0.f, 0.f);
            if (row < NPOS) x = *(const float4*)(outb + (size_t)row * OUTF + c);
            *(float4*)&As[rr][c] = x;
        }
    }
    int q = t & 15, dg = (t >> 4) * 16;
    float acc[16];
#pragma unroll
    for (int i = 0; i < 16; ++i) acc[i] = 0.f;
    for (int k0 = 0; k0 < 256; k0 += 16) {
        __syncthreads();
        {
            int kk = t >> 4, n16 = (t & 15) * 16;
#pragma unroll
            for (int i = 0; i < 4; ++i) {
                float4 x = *(const float4*)(w1 + (size_t)(k0 + kk) * OUTF + n16 + i * 4);
                *(float4*)&Bs[kk][n16 + i * 4] = x;
            }
        }
        __syncthreads();
#pragma unroll
        for (int kk = 0; kk < 16; ++kk) {
            float a = As[q][k0 + kk];
#pragma unroll
            for (int i = 0; i < 16; i += 4) {
                float4 b = *(const float4*)&Bs[kk][dg + i];
                acc[i + 0] += a * b.x; acc[i + 1] += a * b.y;
                acc[i + 2] += a * b.z; acc[i + 3] += a * b.w;
            }
        }
    }
    float x[16];
#pragma unroll
    for (int i = 0; i < 16; ++i) x[i] = acc[i] + b1v[dg + i];
    float ps = 0.f;
#pragma unroll
    for (int i = 0; i < 16; ++i) ps += x[i];
    __syncthreads();
    red[t >> 4][q] = ps;
    __syncthreads();
    float s = 0.f;
#pragma unroll
    for (int i = 0; i < 16; ++i) s += red[i][q];
    float mu = s * (1.0f / 256.0f);
    float pv = 0.f;
#pragma unroll
    for (int i = 0; i < 16; ++i) { float d = x[i] - mu; pv += d * d; }
    __syncthreads();
    red[t >> 4][q] = pv;
    __syncthreads();
    float v = 0.f;
#pragma unroll
    for (int i = 0; i < 16; ++i) v += red[i][q];
    float rs = rsqrtf(v * (1.0f / 256.0f) + 1e-6f);
    int row = m0 + q;
    if (row < NPOS) {
#pragma unroll
        for (int i = 0; i < 16; ++i) {
            int n = dg + i;
            h2o[(size_t)row * OUTF + n] = tanhf((x[i] - mu) * rs * g2[n] + b2v[n]);
        }
    }
}

// ---------------------------------------------------------------------------
// E4: final = h2 @ w2  (no bias) -> d_out
// ---------------------------------------------------------------------------
__global__ __launch_bounds__(256) void e4_final(
    const float* __restrict__ h2in, const float* __restrict__ w2,
    float* __restrict__ outp)
{
    __shared__ float AT[16][68];
    __shared__ float Bs[16][132];
    int t = threadIdx.x;
    int n0 = blockIdx.x * 128;
    int m0 = blockIdx.y * 64;
    float acc[4][8];
#pragma unroll
    for (int i = 0; i < 4; ++i)
#pragma unroll
        for (int j = 0; j < 8; ++j) acc[i][j] = 0.f;
    int mg = (t >> 4) * 4, jg = (t & 15) * 8;
    int am = t & 63, ak = (t >> 6) * 4;
    int bkk = t >> 4, bn = (t & 15) * 8;
    for (int k0 = 0; k0 < 256; k0 += 16) {
        __syncthreads();
        {
            int row = m0 + am;
            float4 v = make_float4(0.f, 0.f, 0.f, 0.f);
            if (row < NPOS) v = *(const float4*)(h2in + (size_t)row * OUTF + k0 + ak);
            AT[ak + 0][am] = v.x; AT[ak + 1][am] = v.y;
            AT[ak + 2][am] = v.z; AT[ak + 3][am] = v.w;
        }
        {
            const float* p = w2 + (size_t)(k0 + bkk) * OUTF + n0 + bn;
            float4 u0 = *(const float4*)p;
            float4 u1 = *(const float4*)(p + 4);
            *(float4*)&Bs[bkk][bn]     = u0;
            *(float4*)&Bs[bkk][bn + 4] = u1;
        }
        __syncthreads();
#pragma unroll
        for (int kk = 0; kk < 16; ++kk) {
            float4 a  = *(const float4*)&AT[kk][mg];
            float4 b0 = *(const float4*)&Bs[kk][jg];
            float4 b1 = *(const float4*)&Bs[kk][jg + 4];
            float av[4] = {a.x, a.y, a.z, a.w};
            float bv_[8] = {b0.x, b0.y, b0.z, b0.w, b1.x, b1.y, b1.z, b1.w};
#pragma unroll
            for (int i = 0; i < 4; ++i)
#pragma unroll
                for (int j = 0; j < 8; ++j) acc[i][j] += av[i] * bv_[j];
        }
    }
#pragma unroll
    for (int i = 0; i < 4; ++i) {
        int row = m0 + mg + i;
        if (row < NPOS) {
#pragma unroll
            for (int j = 0; j < 8; ++j) {
                outp[(size_t)row * OUTF + n0 + jg + j] = acc[i][j];
            }
        }
    }
}

// ---------------------------------------------------------------------------
extern "C" void kernel_launch(void* const* d_in, const int* in_sizes, int n_in,
                              void* d_out, int out_size, void* d_ws, size_t ws_size,
                              hipStream_t stream)
{
    const float* feature = (const float*)d_in[0];
    const float* adj   = (const float*)d_in[1];
    const float* r     = (const float*)d_in[2];
    const float* Wq    = (const float*)d_in[3];
    const float* bq    = (const float*)d_in[4];
    const float* Wk    = (const float*)d_in[5];
    const float* bk    = (const float*)d_in[6];
    const float* Wv    = (const float*)d_in[7];
    const float* bv    = (const float*)d_in[8];
    const float* Ww    = (const float*)d_in[9];
    const float* bw    = (const float*)d_in[10];
    const float* Wr    = (const float*)d_in[11];
    const float* br    = (const float*)d_in[12];
    const float* Wbeta = (const float*)d_in[13];
    const float* bbeta = (const float*)d_in[14];
    const float* ln1g  = (const float*)d_in[15];
    const float* ln1b  = (const float*)d_in[16];
    const float* w1    = (const float*)d_in[17];
    const float* b1    = (const float*)d_in[18];
    const float* ln2g  = (const float*)d_in[19];
    const float* ln2b  = (const float*)d_in[20];
    const float* w2    = (const float*)d_in[21];
    const int*   flag  = (const int*)d_in[22];
    float* out = (float*)d_out;

    // --- workspace layout (liveness-aliased) ---
    char* ws = (char*)d_ws;
    float* LG    = (float*)(ws + 0);
    float* hQ    = (float*)(ws + 30130176);
    float* hK    = (float*)(ws + 35147776);
    float* cc    = (float*)(ws + 30130176);
    float* hV    = (float*)(ws + 40165376);
    float* outb  = (float*)(ws + 40165376);
    float* Hb    = (float*)(ws + 45182976);
    float* hh2   = (float*)(ws + 45182976);
    float* BcP0  = (float*)(ws + 50200576);
    float* BcP1  = (float*)(ws + 60243968);
    float* mpart = (float*)(ws + 70287360);
    float* S     = (float*)(ws + 80322560);

    k0_rp<<<1, 256, 0, stream>>>(r, Wr, br, flag, S);
    k1_proj<<<dim3(8, 77), 256, 0, stream>>>(feature, Wq, bq, Wk, bk, Wv, bv, Ww, bw,
                                             hQ, hK, hV, Hb);
    k2_pgemm<<<dim3(77, 8, 2), 256, 0, stream>>>(hK, adj, S, BcP0, BcP1);
    for (int s = 0; s < NSLAB; ++s) {
        int j0 = s * JS;
        k3a_logits<<<dim3(3, 156), 256, 0, stream>>>(hQ, S, BcP0, BcP1, LG, j0);
        k3b_pv<<<dim3(154, 2), 256, 0, stream>>>(LG, hV, mpart, j0, s == 0 ? 1 : 0);
    }
    e1_relu_ln<<<1225, 256, 0, stream>>>(mpart, Hb, ln1g, ln1b, cc);
    e2_beta<<<dim3(2, 77), 256, 0, stream>>>(cc, Wbeta, bbeta, outb);
    e3_w1_ln2<<<307, 256, 0, stream>>>(outb, w1, b1, ln2g, ln2b, hh2);
    e4_final<<<dim3(2, 77), 256, 0, stream>>>(hh2, w2, out);
}

// Round 5
// 1596.446 us; speedup vs baseline: 1.5308x; 1.1621x over previous
//
#include <hip/hip_runtime.h>
#include <hip/hip_bf16.h>
#include <math.h>

#define NPOS 4900
#define NG1  708
#define NG2  4192
#define INF  512
#define OUTF 256
#define JPAD 4904       // padded j-stride for BcP planes (mult of 8, >= 4900)
#define JS   384        // logits slab width
#define NSLAB 13        // ceil(4900/384)
#define LDS_KS 36       // ushort k-stride (32 + 4 pad): 72B rows, 2-way bank alias (free)

typedef __attribute__((ext_vector_type(8))) short short8;
typedef __attribute__((ext_vector_type(16))) float f32x16;

// ---------------------------------------------------------------------------
// K0: rp = r @ Wr + br  (4x256); store S[0]=rp[ridx], S[1]=rp[2], S[2]=rp[3]
// ---------------------------------------------------------------------------
__global__ __launch_bounds__(256) void k0_rp(
    const float* __restrict__ r, const float* __restrict__ Wr,
    const float* __restrict__ br, const int* __restrict__ flagp,
    float* __restrict__ S)
{
    __shared__ float rsh[1024];
    int t = threadIdx.x;
    for (int i = t; i < 1024; i += 256) rsh[i] = r[i];
    __syncthreads();
    float a0 = 0.f, a1 = 0.f, a2 = 0.f, a3 = 0.f;
    for (int c = 0; c < 256; ++c) {
        float w = Wr[c * 256 + t];
        a0 += rsh[c] * w;
        a1 += rsh[256 + c] * w;
        a2 += rsh[512 + c] * w;
        a3 += rsh[768 + c] * w;
    }
    float b = br[t];
    a0 += b; a1 += b; a2 += b; a3 += b;
    int ridx = (flagp[0] != 0) ? 1 : 0;
    S[t]         = ridx ? a1 : a0;
    S[256 + t]   = a2;
    S[512 + t]   = a3;
}

// ---------------------------------------------------------------------------
// K1: fused projections hQ/hK/hV/H = feature @ {Wq,Wk,Wv,Ww} + bias
// ---------------------------------------------------------------------------
__global__ __launch_bounds__(256) void k1_proj(
    const float* __restrict__ feat,
    const float* __restrict__ Wq, const float* __restrict__ bq,
    const float* __restrict__ Wk, const float* __restrict__ bk,
    const float* __restrict__ Wv, const float* __restrict__ bv,
    const float* __restrict__ Ww, const float* __restrict__ bw,
    float* __restrict__ hQ, float* __restrict__ hK,
    float* __restrict__ hV, float* __restrict__ Hb)
{
    __shared__ float AT[16][68];    // [k][m]
    __shared__ float Bs[16][132];   // [k][n]
    int t = threadIdx.x;
    int mat = blockIdx.x >> 1;
    int n0  = (blockIdx.x & 1) * 128;
    int m0  = blockIdx.y * 64;
    const float* W; const float* bias; float* dst;
    switch (mat) {
        case 0:  W = Wq; bias = bq; dst = hQ; break;
        case 1:  W = Wk; bias = bk; dst = hK; break;
        case 2:  W = Wv; bias = bv; dst = hV; break;
        default: W = Ww; bias = bw; dst = Hb; break;
    }
    float acc[4][8];
#pragma unroll
    for (int i = 0; i < 4; ++i)
#pragma unroll
        for (int j = 0; j < 8; ++j) acc[i][j] = 0.f;
    int mg = (t >> 4) * 4, jg = (t & 15) * 8;
    int am = t & 63, ak = (t >> 6) * 4;
    int bkk = t >> 4, bn = (t & 15) * 8;
    for (int k0 = 0; k0 < INF; k0 += 16) {
        __syncthreads();
        {
            int row = m0 + am;
            float4 v = make_float4(0.f, 0.f, 0.f, 0.f);
            if (row < NPOS) v = *(const float4*)(feat + (size_t)row * INF + k0 + ak);
            AT[ak + 0][am] = v.x; AT[ak + 1][am] = v.y;
            AT[ak + 2][am] = v.z; AT[ak + 3][am] = v.w;
        }
        {
            const float* p = W + (size_t)(k0 + bkk) * OUTF + n0 + bn;
            float4 u0 = *(const float4*)p;
            float4 u1 = *(const float4*)(p + 4);
            *(float4*)&Bs[bkk][bn]     = u0;
            *(float4*)&Bs[bkk][bn + 4] = u1;
        }
        __syncthreads();
#pragma unroll
        for (int kk = 0; kk < 16; ++kk) {
            float4 a  = *(const float4*)&AT[kk][mg];
            float4 b0 = *(const float4*)&Bs[kk][jg];
            float4 b1 = *(const float4*)&Bs[kk][jg + 4];
            float av[4] = {a.x, a.y, a.z, a.w};
            float bv_[8] = {b0.x, b0.y, b0.z, b0.w, b1.x, b1.y, b1.z, b1.w};
#pragma unroll
            for (int i = 0; i < 4; ++i)
#pragma unroll
                for (int j = 0; j < 8; ++j) acc[i][j] += av[i] * bv_[j];
        }
    }
#pragma unroll
    for (int i = 0; i < 4; ++i) {
        int row = m0 + mg + i;
        if (row < NPOS) {
#pragma unroll
            for (int j = 0; j < 8; ++j) {
                int n = n0 + jg + j;
                dst[(size_t)row * OUTF + n] = acc[i][j] + bias[n];
            }
        }
    }
}

// ---------------------------------------------------------------------------
// split2: pack two fp32 into one uint of bf16-hi halves and one of bf16-lo
// residuals (truncation split; combined rel err ~2^-16, lo compensates hi).
// ---------------------------------------------------------------------------
__device__ __forceinline__ void split2(float x0, float x1,
                                       unsigned& hi, unsigned& lo)
{
    unsigned u0 = __float_as_uint(x0), u1 = __float_as_uint(x1);
    unsigned h0 = u0 & 0xFFFF0000u,   h1 = u1 & 0xFFFF0000u;
    float r0 = x0 - __uint_as_float(h0);
    float r1 = x1 - __uint_as_float(h1);
    hi = (h0 >> 16) | h1;
    lo = (__float_as_uint(r0) >> 16) | (__float_as_uint(r1) & 0xFFFF0000u);
}

__device__ __forceinline__ short8 ldfrag(const unsigned short* base, int row, int kuo)
{
    const unsigned long long* p =
        (const unsigned long long*)(base + row * LDS_KS + kuo);
    union { unsigned long long q[2]; short8 s; } u;
    u.q[0] = p[0];
    u.q[1] = p[1];
    return u.s;
}

// ---------------------------------------------------------------------------
// K2 (MFMA split-bf16): BcP[part][g*256+h*64+dd][j] = sum_k A[g,dd][k]*adj[rowoff+k][j]
//   A[g,dd][k] = hKpart[(h*L+k)*64+dd] * 0.5 * S[g+part][(k&3)*64+dd]
// Tile M=128 (g0 dd0..63 | g1 dd0..63), N=64, BK=32. Grid (77, 4h, 2part).
// 4 waves; wave w owns m-rows [w*32, w*32+32) x both 32-col n-blocks.
// Split-bf16: D += Ah*Bh + Ah*Bl + Al*Bh  (32x32x16 bf16 MFMA, fp32 acc).
// ---------------------------------------------------------------------------
__global__ __launch_bounds__(256) void k2_mfma(
    const float* __restrict__ hK, const float* __restrict__ adj,
    const float* __restrict__ S,
    float* __restrict__ BcP0, float* __restrict__ BcP1)
{
    __shared__ unsigned short sAh[128 * LDS_KS];
    __shared__ unsigned short sAl[128 * LDS_KS];
    __shared__ unsigned short sBh[64 * LDS_KS];
    __shared__ unsigned short sBl[64 * LDS_KS];

    int t = threadIdx.x;
    int j0 = blockIdx.x * 64;
    int h  = blockIdx.y;
    int part = blockIdx.z;
    int L = part ? NG2 : NG1;
    const float* kflat = hK + (part ? (size_t)NG1 * OUTF : 0);
    int rowoff = part ? NG1 : 0;
    float* dst = part ? BcP1 : BcP0;

    int dd = t & 63;          // staging lane: dd for A, n for B
    int kg = t >> 6;          // k-group 0..3 (== wave id)
    int jcol = j0 + dd;

    // per-thread scale registers sc[g][c], c = k&3
    float sc[2][4];
#pragma unroll
    for (int g = 0; g < 2; ++g)
#pragma unroll
        for (int c = 0; c < 4; ++c)
            sc[g][c] = 0.5f * S[(g + part) * 256 + c * 64 + dd];

    f32x16 acc0, acc1;
#pragma unroll
    for (int i = 0; i < 16; ++i) { acc0[i] = 0.f; acc1[i] = 0.f; }

    int lane = t & 63;
    int half = lane >> 5;
    int ml = lane & 31;
    int arow = kg * 32 + ml;          // this wave's A-row for its frags

    unsigned* uAh = (unsigned*)sAh;
    unsigned* uAl = (unsigned*)sAl;
    unsigned* uBh = (unsigned*)sBh;
    unsigned* uBl = (unsigned*)sBl;

    int Ksteps = (L + 31) >> 5;
    for (int ks = 0; ks < Ksteps; ++ks) {
        int k0 = ks * 32;
        // global loads (coalesced: 64 lanes contiguous in dd / jcol)
        float xa[8], xb[8];
#pragma unroll
        for (int i = 0; i < 8; ++i) {
            int kv = k0 + kg * 8 + i;
            bool okk = (kv < L);
            xa[i] = okk ? kflat[(size_t)(h * L + kv) * 64 + dd] : 0.f;
            xb[i] = (okk && jcol < NPOS)
                        ? adj[(size_t)(rowoff + kv) * NPOS + jcol] : 0.f;
        }
        // split to bf16 hi/lo packed pairs
        unsigned hA0[4], lA0[4], hA1[4], lA1[4], hB[4], lB[4];
#pragma unroll
        for (int i = 0; i < 8; i += 2) {
            float a0 = xa[i] * sc[0][i & 3];
            float a1 = xa[i + 1] * sc[0][(i + 1) & 3];
            split2(a0, a1, hA0[i >> 1], lA0[i >> 1]);
            float c0 = xa[i] * sc[1][i & 3];
            float c1 = xa[i + 1] * sc[1][(i + 1) & 3];
            split2(c0, c1, hA1[i >> 1], lA1[i >> 1]);
            split2(xb[i], xb[i + 1], hB[i >> 1], lB[i >> 1]);
        }
        __syncthreads();   // prev iteration's frag reads complete
        {
            int b0 = dd * 18 + kg * 4;          // uint index, g0 row = dd
            int b1 = (64 + dd) * 18 + kg * 4;   // g1 row = 64+dd
            *(uint2*)(uAh + b0)     = make_uint2(hA0[0], hA0[1]);
            *(uint2*)(uAh + b0 + 2) = make_uint2(hA0[2], hA0[3]);
            *(uint2*)(uAl + b0)     = make_uint2(lA0[0], lA0[1]);
            *(uint2*)(uAl + b0 + 2) = make_uint2(lA0[2], lA0[3]);
            *(uint2*)(uAh + b1)     = make_uint2(hA1[0], hA1[1]);
            *(uint2*)(uAh + b1 + 2) = make_uint2(hA1[2], hA1[3]);
            *(uint2*)(uAl + b1)     = make_uint2(lA1[0], lA1[1]);
            *(uint2*)(uAl + b1 + 2) = make_uint2(lA1[2], lA1[3]);
            *(uint2*)(uBh + b0)     = make_uint2(hB[0], hB[1]);
            *(uint2*)(uBh + b0 + 2) = make_uint2(hB[2], hB[3]);
            *(uint2*)(uBl + b0)     = make_uint2(lB[0], lB[1]);
            *(uint2*)(uBl + b0 + 2) = make_uint2(lB[2], lB[3]);
        }
        __syncthreads();   // staging visible
#pragma unroll
        for (int kq = 0; kq < 2; ++kq) {
            int kuo = kq * 16 + half * 8;      // ushort offset within row
            short8 aH = ldfrag(sAh, arow, kuo);
            short8 aL = ldfrag(sAl, arow, kuo);
            short8 b0H = ldfrag(sBh, ml, kuo);
            short8 b0L = ldfrag(sBl, ml, kuo);
            short8 b1H = ldfrag(sBh, 32 + ml, kuo);
            short8 b1L = ldfrag(sBl, 32 + ml, kuo);
            acc0 = __builtin_amdgcn_mfma_f32_32x32x16_bf16(aH, b0H, acc0, 0, 0, 0);
            acc0 = __builtin_amdgcn_mfma_f32_32x32x16_bf16(aH, b0L, acc0, 0, 0, 0);
            acc0 = __builtin_amdgcn_mfma_f32_32x32x16_bf16(aL, b0H, acc0, 0, 0, 0);
            acc1 = __builtin_amdgcn_mfma_f32_32x32x16_bf16(aH, b1H, acc1, 0, 0, 0);
            acc1 = __builtin_amdgcn_mfma_f32_32x32x16_bf16(aH, b1L, acc1, 0, 0, 0);
            acc1 = __builtin_amdgcn_mfma_f32_32x32x16_bf16(aL, b1H, acc1, 0, 0, 0);
        }
    }

    // epilogue: C/D layout col=lane&31, row=(reg&3)+8*(reg>>2)+4*(lane>>5)
    int col0 = j0 + ml;        // always < NPOS (max 4895)
    int col1 = j0 + 32 + ml;   // may exceed; zero-fill [NPOS, JPAD)
#pragma unroll
    for (int reg = 0; reg < 16; ++reg) {
        int m = kg * 32 + (reg & 3) + 8 * (reg >> 2) + 4 * half;
        int orow = (m >> 6) * 256 + h * 64 + (m & 63);
        dst[(size_t)orow * JPAD + col0] = acc0[reg];
        if (col1 < JPAD)
            dst[(size_t)orow * JPAD + col1] = (col1 < NPOS) ? acc1[reg] : 0.f;
    }
}

// ---------------------------------------------------------------------------
// K3a: logits slab GEMM.  LG[h][pos][jloc] = Q~[h,pos][0:128] . BcP[:, j0+jloc]
// K<64 from BcP0, K>=64 from BcP1.  Tile M=128, N=128, K=128.
// ---------------------------------------------------------------------------
__global__ __launch_bounds__(256) void k3a_logits(
    const float* __restrict__ hQ, const float* __restrict__ S,
    const float* __restrict__ BcP0, const float* __restrict__ BcP1,
    float* __restrict__ LG, int j0)
{
    __shared__ float As[16][132];    // [kk][m]
    __shared__ float BsA[16][68];    // cols jg..jg+3
    __shared__ float BsB[16][68];    // cols jg+4..jg+7
    int t = threadIdx.x;
    int n0 = blockIdx.x * 128;       // 0,128,256 within slab
    int y = blockIdx.y;              // 156 = 4h * 39
    int h = y / 39, rr = y % 39;
    int g, tile;
    if (rr < 6) { g = 0; tile = rr; } else { g = 1; tile = rr - 6; }
    int Lg = g ? NG2 : NG1;
    int vbase = g ? NG1 * OUTF : 0;
    int posbase = g ? NG1 : 0;
    int q0 = tile * 128;

    float acc[8][8];
#pragma unroll
    for (int i = 0; i < 8; ++i)
#pragma unroll
        for (int j = 0; j < 8; ++j) acc[i][j] = 0.f;
    int mg = (t >> 4) * 8, jg = (t & 15) * 8;
    int u = t & 15;
    int bkk = t >> 4;

    for (int k0 = 0; k0 < 128; k0 += 16) {
        int p = k0 >> 6;
        __syncthreads();
        // stage A (Q scaled): 512 float4 slots, 2 per thread
#pragma unroll
        for (int i = 0; i < 2; ++i) {
            int s = t + i * 256;
            int m = s >> 2, kq = (s & 3) * 4;
            int d = (k0 & 63) + kq;
            int ql = q0 + m;
            float4 v = make_float4(0.f, 0.f, 0.f, 0.f);
            if (ql < Lg) {
                float4 qv = *(const float4*)(hQ + vbase + (size_t)(h * Lg + ql) * 64 + d);
                float4 sv = *(const float4*)(S + (g + p) * 256 + (ql & 3) * 64 + d);
                v = make_float4(qv.x * sv.x, qv.y * sv.y, qv.z * sv.z, qv.w * sv.w);
            }
            As[kq + 0][m] = v.x; As[kq + 1][m] = v.y;
            As[kq + 2][m] = v.z; As[kq + 3][m] = v.w;
        }
        // stage B from part plane (de-interleaved)
        {
            const float* plane = p ? BcP1 : BcP0;
            int row = (g * 4 + h) * 64 + (k0 & 63) + bkk;
            int col = j0 + n0 + u * 8;
            float4 c0 = make_float4(0.f, 0.f, 0.f, 0.f);
            float4 c1 = make_float4(0.f, 0.f, 0.f, 0.f);
            if (col + 7 < JPAD) {
                const float* pp = plane + (size_t)row * JPAD + col;
                c0 = *(const float4*)pp;
                c1 = *(const float4*)(pp + 4);
            }
            *(float4*)&BsA[bkk][u * 4] = c0;
            *(float4*)&BsB[bkk][u * 4] = c1;
        }
        __syncthreads();
#pragma unroll
        for (int kk = 0; kk < 16; ++kk) {
            float4 a0 = *(const float4*)&As[kk][mg];
            float4 a1 = *(const float4*)&As[kk][mg + 4];
            float4 b0 = *(const float4*)&BsA[kk][u * 4];
            float4 b1 = *(const float4*)&BsB[kk][u * 4];
            float av[8] = {a0.x, a0.y, a0.z, a0.w, a1.x, a1.y, a1.z, a1.w};
            float bv_[8] = {b0.x, b0.y, b0.z, b0.w, b1.x, b1.y, b1.z, b1.w};
#pragma unroll
            for (int i = 0; i < 8; ++i)
#pragma unroll
                for (int j = 0; j < 8; ++j) acc[i][j] += av[i] * bv_[j];
        }
    }
#pragma unroll
    for (int i = 0; i < 8; ++i) {
        int ql = q0 + mg + i;
        if (ql < Lg) {
            float* pp = LG + ((size_t)h * NPOS + posbase + ql) * JS + n0 + jg;
            *(float4*)pp       = make_float4(acc[i][0], acc[i][1], acc[i][2], acc[i][3]);
            *(float4*)(pp + 4) = make_float4(acc[i][4], acc[i][5], acc[i][6], acc[i][7]);
        }
    }
}

// ---------------------------------------------------------------------------
// K3b: PV slab GEMM, ALL 4 heads per block (LG read exactly once).
// Block: 32 pos x 256 ch; j-range = ks*192..+192 within slab.
// mpart[ks][pos][ch] += softmax_h(LG[:,pos,j]) . V
// ---------------------------------------------------------------------------
__global__ __launch_bounds__(256) void k3b_pv(
    const float* __restrict__ LG, const float* __restrict__ hV,
    float* __restrict__ mpart, int j0, int first)
{
    __shared__ float Asm[4][16][34];   // [h][jj][pos]  alpha
    __shared__ float Bsv[16][264];     // [jj][ch]      V
    int t = threadIdx.x;
    int m0 = blockIdx.x * 32;          // global pos tile
    int ks = blockIdx.y;
    int jbase = ks * 192;

    float acc[2][16];
#pragma unroll
    for (int i = 0; i < 2; ++i)
#pragma unroll
        for (int j = 0; j < 16; ++j) acc[i][j] = 0.f;
    int pos2 = (t & 15) * 2;
    int ch16 = (t >> 4) * 16;
    int hch  = ch16 >> 6;
    int sj = t & 15, sp = t >> 4;

    for (int kc = 0; kc < 192; kc += 16) {
        __syncthreads();
        // stage V: 1024 float4 slots, 4 per thread
#pragma unroll
        for (int i = 0; i < 4; ++i) {
            int s = t + i * 256;
            int jj = s >> 6, c4 = (s & 63) * 4;
            int h = c4 >> 6, d = c4 & 63;
            int jglob = j0 + jbase + kc + jj;
            float4 x = make_float4(0.f, 0.f, 0.f, 0.f);
            if (jglob < NPOS)
                x = *(const float4*)(hV + ((size_t)h * NPOS + jglob) * 64 + d);
            *(float4*)&Bsv[jj][c4] = x;
        }
        // stage alpha: 32 pos x 16 j = 512 pairs, 2 per thread; softmax over heads
#pragma unroll
        for (int i = 0; i < 2; ++i) {
            int posl = sp + 16 * i;
            int pos = m0 + posl;
            int jglob = j0 + jbase + kc + sj;
            float v0 = 0.f, v1 = 0.f, v2 = 0.f, v3 = 0.f;
            if (pos < NPOS) {
                size_t base = (size_t)pos * JS + jbase + kc + sj;
                v0 = LG[base];
                v1 = LG[(size_t)NPOS * JS + base];
                v2 = LG[(size_t)2 * NPOS * JS + base];
                v3 = LG[(size_t)3 * NPOS * JS + base];
            }
            float mx = fmaxf(fmaxf(v0, v1), fmaxf(v2, v3));
            float e0 = __expf(v0 - mx), e1 = __expf(v1 - mx);
            float e2 = __expf(v2 - mx), e3 = __expf(v3 - mx);
            float inv = 1.0f / (e0 + e1 + e2 + e3);
            bool ok = (pos < NPOS) && (jglob < NPOS);
            float z = ok ? inv : 0.f;
            Asm[0][sj][posl] = e0 * z;
            Asm[1][sj][posl] = e1 * z;
            Asm[2][sj][posl] = e2 * z;
            Asm[3][sj][posl] = e3 * z;
        }
        __syncthreads();
#pragma unroll
        for (int kk = 0; kk < 16; ++kk) {
            float2 a = *(const float2*)&Asm[hch][kk][pos2];
            float4 b0 = *(const float4*)&Bsv[kk][ch16 + 0];
            float4 b1 = *(const float4*)&Bsv[kk][ch16 + 4];
            float4 b2 = *(const float4*)&Bsv[kk][ch16 + 8];
            float4 b3 = *(const float4*)&Bsv[kk][ch16 + 12];
            float bv_[16] = {b0.x, b0.y, b0.z, b0.w, b1.x, b1.y, b1.z, b1.w,
                             b2.x, b2.y, b2.z, b2.w, b3.x, b3.y, b3.z, b3.w};
#pragma unroll
            for (int j = 0; j < 16; ++j) {
                acc[0][j] += a.x * bv_[j];
                acc[1][j] += a.y * bv_[j];
            }
        }
    }
#pragma unroll
    for (int i = 0; i < 2; ++i) {
        int pos = m0 + pos2 + i;
        if (pos < NPOS) {
            float* pp = mpart + ((size_t)ks * NPOS + pos) * OUTF + ch16;
#pragma unroll
            for (int c = 0; c < 16; c += 4) {
                float4 prev = first ? make_float4(0.f, 0.f, 0.f, 0.f)
                                    : *(const float4*)(pp + c);
                *(float4*)(pp + c) = make_float4(prev.x + acc[i][c + 0],
                                                 prev.y + acc[i][c + 1],
                                                 prev.z + acc[i][c + 2],
                                                 prev.w + acc[i][c + 3]);
            }
        }
    }
}

// ---------------------------------------------------------------------------
// E1: m = mpart0+mpart1; relu; ln1; write concat buffer [H | ln1(relu(m))]
// ---------------------------------------------------------------------------
__global__ __launch_bounds__(256) void e1_relu_ln(
    const float* __restrict__ mpart, const float* __restrict__ Hb,
    const float* __restrict__ g1, const float* __restrict__ b1,
    float* __restrict__ cc)
{
    int w = threadIdx.x >> 6, lane = threadIdx.x & 63;
    int row = blockIdx.x * 4 + w;
    int c = lane * 4;
    float4 x0 = *(const float4*)(mpart + (size_t)row * OUTF + c);
    float4 x1 = *(const float4*)(mpart + (size_t)NPOS * OUTF + (size_t)row * OUTF + c);
    float x[4] = { fmaxf(x0.x + x1.x, 0.f), fmaxf(x0.y + x1.y, 0.f),
                   fmaxf(x0.z + x1.z, 0.f), fmaxf(x0.w + x1.w, 0.f) };
    float s = x[0] + x[1] + x[2] + x[3];
#pragma unroll
    for (int m = 32; m > 0; m >>= 1) s += __shfl_xor(s, m, 64);
    float mu = s * (1.0f / 256.0f);
    float vs = 0.f;
#pragma unroll
    for (int i = 0; i < 4; ++i) { float d = x[i] - mu; vs += d * d; }
#pragma unroll
    for (int m = 32; m > 0; m >>= 1) vs += __shfl_xor(vs, m, 64);
    float rs = rsqrtf(vs * (1.0f / 256.0f) + 1e-5f);
    float4 y;
    y.x = (x[0] - mu) * rs * g1[c + 0] + b1[c + 0];
    y.y = (x[1] - mu) * rs * g1[c + 1] + b1[c + 1];
    y.z = (x[2] - mu) * rs * g1[c + 2] + b1[c + 2];
    y.w = (x[3] - mu) * rs * g1[c + 3] + b1[c + 3];
    *(float4*)(cc + (size_t)row * INF + OUTF + c) = y;
    float4 hh = *(const float4*)(Hb + (size_t)row * OUTF + c);
    *(float4*)(cc + (size_t)row * INF + c) = hh;
}

// ---------------------------------------------------------------------------
// E2: beta = sigmoid(cc @ Wbeta + bbeta); out = beta*m1 + (1-beta)*H
// ---------------------------------------------------------------------------
__global__ __launch_bounds__(256) void e2_beta(
    const float* __restrict__ cc, const float* __restrict__ Wb,
    const float* __restrict__ bb, float* __restrict__ outb)
{
    __shared__ float AT[16][68];
    __shared__ float Bs[16][132];
    int t = threadIdx.x;
    int n0 = blockIdx.x * 128;
    int m0 = blockIdx.y * 64;
    float acc[4][8];
#pragma unroll
    for (int i = 0; i < 4; ++i)
#pragma unroll
        for (int j = 0; j < 8; ++j) acc[i][j] = 0.f;
    int mg = (t >> 4) * 4, jg = (t & 15) * 8;
    int am = t & 63, ak = (t >> 6) * 4;
    int bkk = t >> 4, bn = (t & 15) * 8;
    for (int k0 = 0; k0 < INF; k0 += 16) {
        __syncthreads();
        {
            int row = m0 + am;
            float4 v = make_float4(0.f, 0.f, 0.f, 0.f);
            if (row < NPOS) v = *(const float4*)(cc + (size_t)row * INF + k0 + ak);
            AT[ak + 0][am] = v.x; AT[ak + 1][am] = v.y;
            AT[ak + 2][am] = v.z; AT[ak + 3][am] = v.w;
        }
        {
            const float* p = Wb + (size_t)(k0 + bkk) * OUTF + n0 + bn;
            float4 u0 = *(const float4*)p;
            float4 u1 = *(const float4*)(p + 4);
            *(float4*)&Bs[bkk][bn]     = u0;
            *(float4*)&Bs[bkk][bn + 4] = u1;
        }
        __syncthreads();
#pragma unroll
        for (int kk = 0; kk < 16; ++kk) {
            float4 a  = *(const float4*)&AT[kk][mg];
            float4 b0 = *(const float4*)&Bs[kk][jg];
            float4 b1 = *(const float4*)&Bs[kk][jg + 4];
            float av[4] = {a.x, a.y, a.z, a.w};
            float bv_[8] = {b0.x, b0.y, b0.z, b0.w, b1.x, b1.y, b1.z, b1.w};
#pragma unroll
            for (int i = 0; i < 4; ++i)
#pragma unroll
                for (int j = 0; j < 8; ++j) acc[i][j] += av[i] * bv_[j];
        }
    }
#pragma unroll
    for (int i = 0; i < 4; ++i) {
        int row = m0 + mg + i;
        if (row < NPOS) {
#pragma unroll
            for (int j = 0; j < 8; ++j) {
                int n = n0 + jg + j;
                float x = acc[i][j] + bb[n];
                float sg = 1.0f / (1.0f + __expf(-x));
                float m1v = cc[(size_t)row * INF + OUTF + n];
                float Hv  = cc[(size_t)row * INF + n];
                outb[(size_t)row * OUTF + n] = sg * m1v + (1.0f - sg) * Hv;
            }
        }
    }
}

// ---------------------------------------------------------------------------
// E3: t = out @ w1 + b1 ; ln2(eps=1e-6) ; tanh -> h2.
// ---------------------------------------------------------------------------
__global__ __launch_bounds__(256) void e3_w1_ln2(
    const float* __restrict__ outb, const float* __restrict__ w1,
    const float* __restrict__ b1v, const float* __restrict__ g2,
    const float* __restrict__ b2v, float* __restrict__ h2o)
{
    __shared__ float As[16][260];
    __shared__ float Bs[16][260];
    __shared__ float red[16][17];
    int t = threadIdx.x;
    int m0 = blockIdx.x * 16;
    {
        int rr = t >> 4, c4 = (t & 15) * 4;
        int row = m0 + rr;
#pragma unroll
        for (int i = 0; i < 4; ++i) {
            int c = c4 + i * 64;
            float4 x = make_float4(0.f, 0.f, 0.f, 0.f);
            if (row < NPOS) x = *(const float4*)(outb + (size_t)row * OUTF + c);
            *(float4*)&As[rr][c] = x;
        }
    }
    int q = t & 15, dg = (t >> 4) * 16;
    float acc[16];
#pragma unroll
    for (int i = 0; i < 16; ++i) acc[i] = 0.f;
    for (int k0 = 0; k0 < 256; k0 += 16) {
        __syncthreads();
        {
            int kk = t >> 4, n16 = (t & 15) * 16;
#pragma unroll
            for (int i = 0; i < 4; ++i) {
                float4 x = *(const float4*)(w1 + (size_t)(k0 + kk) * OUTF + n16 + i * 4);
                *(float4*)&Bs[kk][n16 + i * 4] = x;
            }
        }
        __syncthreads();
#pragma unroll
        for (int kk = 0; kk < 16; ++kk) {
            float a = As[q][k0 + kk];
#pragma unroll
            for (int i = 0; i < 16; i += 4) {
                float4 b = *(const float4*)&Bs[kk][dg + i];
                acc[i + 0] += a * b.x; acc[i + 1] += a * b.y;
                acc[i + 2] += a * b.z; acc[i + 3] += a * b.w;
            }
        }
    }
    float x[16];
#pragma unroll
    for (int i = 0; i < 16; ++i) x[i] = acc[i] + b1v[dg + i];
    float ps = 0.f;
#pragma unroll
    for (int i = 0; i < 16; ++i) ps += x[i];
    __syncthreads();
    red[t >> 4][q] = ps;
    __syncthreads();
    float s = 0.f;
#pragma unroll
    for (int i = 0; i < 16; ++i) s += red[i][q];
    float mu = s * (1.0f / 256.0f);
    float pv = 0.f;
#pragma unroll
    for (int i = 0; i < 16; ++i) { float d = x[i] - mu; pv += d * d; }
    __syncthreads();
    red[t >> 4][q] = pv;
    __syncthreads();
    float v = 0.f;
#pragma unroll
    for (int i = 0; i < 16; ++i) v += red[i][q];
    float rs = rsqrtf(v * (1.0f / 256.0f) + 1e-6f);
    int row = m0 + q;
    if (row < NPOS) {
#pragma unroll
        for (int i = 0; i < 16; ++i) {
            int n = dg + i;
            h2o[(size_t)row * OUTF + n] = tanhf((x[i] - mu) * rs * g2[n] + b2v[n]);
        }
    }
}

// ---------------------------------------------------------------------------
// E4: final = h2 @ w2  (no bias) -> d_out
// ---------------------------------------------------------------------------
__global__ __launch_bounds__(256) void e4_final(
    const float* __restrict__ h2in, const float* __restrict__ w2,
    float* __restrict__ outp)
{
    __shared__ float AT[16][68];
    __shared__ float Bs[16][132];
    int t = threadIdx.x;
    int n0 = blockIdx.x * 128;
    int m0 = blockIdx.y * 64;
    float acc[4][8];
#pragma unroll
    for (int i = 0; i < 4; ++i)
#pragma unroll
        for (int j = 0; j < 8; ++j) acc[i][j] = 0.f;
    int mg = (t >> 4) * 4, jg = (t & 15) * 8;
    int am = t & 63, ak = (t >> 6) * 4;
    int bkk = t >> 4, bn = (t & 15) * 8;
    for (int k0 = 0; k0 < 256; k0 += 16) {
        __syncthreads();
        {
            int row = m0 + am;
            float4 v = make_float4(0.f, 0.f, 0.f, 0.f);
            if (row < NPOS) v = *(const float4*)(h2in + (size_t)row * OUTF + k0 + ak);
            AT[ak + 0][am] = v.x; AT[ak + 1][am] = v.y;
            AT[ak + 2][am] = v.z; AT[ak + 3][am] = v.w;
        }
        {
            const float* p = w2 + (size_t)(k0 + bkk) * OUTF + n0 + bn;
            float4 u0 = *(const float4*)p;
            float4 u1 = *(const float4*)(p + 4);
            *(float4*)&Bs[bkk][bn]     = u0;
            *(float4*)&Bs[bkk][bn + 4] = u1;
        }
        __syncthreads();
#pragma unroll
        for (int kk = 0; kk < 16; ++kk) {
            float4 a  = *(const float4*)&AT[kk][mg];
            float4 b0 = *(const float4*)&Bs[kk][jg];
            float4 b1 = *(const float4*)&Bs[kk][jg + 4];
            float av[4] = {a.x, a.y, a.z, a.w};
            float bv_[8] = {b0.x, b0.y, b0.z, b0.w, b1.x, b1.y, b1.z, b1.w};
#pragma unroll
            for (int i = 0; i < 4; ++i)
#pragma unroll
                for (int j = 0; j < 8; ++j) acc[i][j] += av[i] * bv_[j];
        }
    }
#pragma unroll
    for (int i = 0; i < 4; ++i) {
        int row = m0 + mg + i;
        if (row < NPOS) {
#pragma unroll
            for (int j = 0; j < 8; ++j) {
                outp[(size_t)row * OUTF + n0 + jg + j] = acc[i][j];
            }
        }
    }
}

// ---------------------------------------------------------------------------
extern "C" void kernel_launch(void* const* d_in, const int* in_sizes, int n_in,
                              void* d_out, int out_size, void* d_ws, size_t ws_size,
                              hipStream_t stream)
{
    const float* feature = (const float*)d_in[0];
    const float* adj   = (const float*)d_in[1];
    const float* r     = (const float*)d_in[2];
    const float* Wq    = (const float*)d_in[3];
    const float* bq    = (const float*)d_in[4];
    const float* Wk    = (const float*)d_in[5];
    const float* bk    = (const float*)d_in[6];
    const float* Wv    = (const float*)d_in[7];
    const float* bv    = (const float*)d_in[8];
    const float* Ww    = (const float*)d_in[9];
    const float* bw    = (const float*)d_in[10];
    const float* Wr    = (const float*)d_in[11];
    const float* br    = (const float*)d_in[12];
    const float* Wbeta = (const float*)d_in[13];
    const float* bbeta = (const float*)d_in[14];
    const float* ln1g  = (const float*)d_in[15];
    const float* ln1b  = (const float*)d_in[16];
    const float* w1    = (const float*)d_in[17];
    const float* b1    = (const float*)d_in[18];
    const float* ln2g  = (const float*)d_in[19];
    const float* ln2b  = (const float*)d_in[20];
    const float* w2    = (const float*)d_in[21];
    const int*   flag  = (const int*)d_in[22];
    float* out = (float*)d_out;

    // --- workspace layout (liveness-aliased) ---
    char* ws = (char*)d_ws;
    float* LG    = (float*)(ws + 0);
    float* hQ    = (float*)(ws + 30130176);
    float* hK    = (float*)(ws + 35147776);
    float* cc    = (float*)(ws + 30130176);
    float* hV    = (float*)(ws + 40165376);
    float* outb  = (float*)(ws + 40165376);
    float* Hb    = (float*)(ws + 45182976);
    float* hh2   = (float*)(ws + 45182976);
    float* BcP0  = (float*)(ws + 50200576);
    float* BcP1  = (float*)(ws + 60243968);
    float* mpart = (float*)(ws + 70287360);
    float* S     = (float*)(ws + 80322560);

    k0_rp<<<1, 256, 0, stream>>>(r, Wr, br, flag, S);
    k1_proj<<<dim3(8, 77), 256, 0, stream>>>(feature, Wq, bq, Wk, bk, Wv, bv, Ww, bw,
                                             hQ, hK, hV, Hb);
    k2_mfma<<<dim3(77, 4, 2), 256, 0, stream>>>(hK, adj, S, BcP0, BcP1);
    for (int s = 0; s < NSLAB; ++s) {
        int j0 = s * JS;
        k3a_logits<<<dim3(3, 156), 256, 0, stream>>>(hQ, S, BcP0, BcP1, LG, j0);
        k3b_pv<<<dim3(154, 2), 256, 0, stream>>>(LG, hV, mpart, j0, s == 0 ? 1 : 0);
    }
    e1_relu_ln<<<1225, 256, 0, stream>>>(mpart, Hb, ln1g, ln1b, cc);
    e2_beta<<<dim3(2, 77), 256, 0, stream>>>(cc, Wbeta, bbeta, outb);
    e3_w1_ln2<<<307, 256, 0, stream>>>(outb, w1, b1, ln2g, ln2b, hh2);
    e4_final<<<dim3(2, 77), 256, 0, stream>>>(hh2, w2, out);
}

// Round 6
// 1404.450 us; speedup vs baseline: 1.7401x; 1.1367x over previous
//
#include <hip/hip_runtime.h>
#include <hip/hip_bf16.h>
#include <math.h>

#define NPOS 4900
#define NG1  708
#define NG2  4192
#define INF  512
#define OUTF 256
#define JB   4904       // B' j-row count (rows 4900..4903 zeroed)
#define JS   384        // logits slab width
#define NSLAB 13        // ceil(4900/384)
#define LDS_KS 36       // k2: ushort k-stride (32 + 4 pad)

typedef __attribute__((ext_vector_type(8))) short short8;
typedef __attribute__((ext_vector_type(16))) float f32x16;

// ---------------------------------------------------------------------------
// K0: rp = r @ Wr + br  (4x256); store S[0]=rp[ridx], S[1]=rp[2], S[2]=rp[3]
// ---------------------------------------------------------------------------
__global__ __launch_bounds__(256) void k0_rp(
    const float* __restrict__ r, const float* __restrict__ Wr,
    const float* __restrict__ br, const int* __restrict__ flagp,
    float* __restrict__ S)
{
    __shared__ float rsh[1024];
    int t = threadIdx.x;
    for (int i = t; i < 1024; i += 256) rsh[i] = r[i];
    __syncthreads();
    float a0 = 0.f, a1 = 0.f, a2 = 0.f, a3 = 0.f;
    for (int c = 0; c < 256; ++c) {
        float w = Wr[c * 256 + t];
        a0 += rsh[c] * w;
        a1 += rsh[256 + c] * w;
        a2 += rsh[512 + c] * w;
        a3 += rsh[768 + c] * w;
    }
    float b = br[t];
    a0 += b; a1 += b; a2 += b; a3 += b;
    int ridx = (flagp[0] != 0) ? 1 : 0;
    S[t]         = ridx ? a1 : a0;
    S[256 + t]   = a2;
    S[512 + t]   = a3;
}

// ---------------------------------------------------------------------------
// K1: fused projections hQ/hK/hV/H = feature @ {Wq,Wk,Wv,Ww} + bias
// ---------------------------------------------------------------------------
__global__ __launch_bounds__(256) void k1_proj(
    const float* __restrict__ feat,
    const float* __restrict__ Wq, const float* __restrict__ bq,
    const float* __restrict__ Wk, const float* __restrict__ bk,
    const float* __restrict__ Wv, const float* __restrict__ bv,
    const float* __restrict__ Ww, const float* __restrict__ bw,
    float* __restrict__ hQ, float* __restrict__ hK,
    float* __restrict__ hV, float* __restrict__ Hb)
{
    __shared__ float AT[16][68];    // [k][m]
    __shared__ float Bs[16][132];   // [k][n]
    int t = threadIdx.x;
    int mat = blockIdx.x >> 1;
    int n0  = (blockIdx.x & 1) * 128;
    int m0  = blockIdx.y * 64;
    const float* W; const float* bias; float* dst;
    switch (mat) {
        case 0:  W = Wq; bias = bq; dst = hQ; break;
        case 1:  W = Wk; bias = bk; dst = hK; break;
        case 2:  W = Wv; bias = bv; dst = hV; break;
        default: W = Ww; bias = bw; dst = Hb; break;
    }
    float acc[4][8];
#pragma unroll
    for (int i = 0; i < 4; ++i)
#pragma unroll
        for (int j = 0; j < 8; ++j) acc[i][j] = 0.f;
    int mg = (t >> 4) * 4, jg = (t & 15) * 8;
    int am = t & 63, ak = (t >> 6) * 4;
    int bkk = t >> 4, bn = (t & 15) * 8;
    for (int k0 = 0; k0 < INF; k0 += 16) {
        __syncthreads();
        {
            int row = m0 + am;
            float4 v = make_float4(0.f, 0.f, 0.f, 0.f);
            if (row < NPOS) v = *(const float4*)(feat + (size_t)row * INF + k0 + ak);
            AT[ak + 0][am] = v.x; AT[ak + 1][am] = v.y;
            AT[ak + 2][am] = v.z; AT[ak + 3][am] = v.w;
        }
        {
            const float* p = W + (size_t)(k0 + bkk) * OUTF + n0 + bn;
            float4 u0 = *(const float4*)p;
            float4 u1 = *(const float4*)(p + 4);
            *(float4*)&Bs[bkk][bn]     = u0;
            *(float4*)&Bs[bkk][bn + 4] = u1;
        }
        __syncthreads();
#pragma unroll
        for (int kk = 0; kk < 16; ++kk) {
            float4 a  = *(const float4*)&AT[kk][mg];
            float4 b0 = *(const float4*)&Bs[kk][jg];
            float4 b1 = *(const float4*)&Bs[kk][jg + 4];
            float av[4] = {a.x, a.y, a.z, a.w};
            float bv_[8] = {b0.x, b0.y, b0.z, b0.w, b1.x, b1.y, b1.z, b1.w};
#pragma unroll
            for (int i = 0; i < 4; ++i)
#pragma unroll
                for (int j = 0; j < 8; ++j) acc[i][j] += av[i] * bv_[j];
        }
    }
#pragma unroll
    for (int i = 0; i < 4; ++i) {
        int row = m0 + mg + i;
        if (row < NPOS) {
#pragma unroll
            for (int j = 0; j < 8; ++j) {
                int n = n0 + jg + j;
                dst[(size_t)row * OUTF + n] = acc[i][j] + bias[n];
            }
        }
    }
}

// ---------------------------------------------------------------------------
// split helpers (truncation split: x = hi(bf16) + lo(bf16), rel err ~2^-16)
// ---------------------------------------------------------------------------
__device__ __forceinline__ void split2(float x0, float x1,
                                       unsigned& hi, unsigned& lo)
{
    unsigned u0 = __float_as_uint(x0), u1 = __float_as_uint(x1);
    unsigned h0 = u0 & 0xFFFF0000u,   h1 = u1 & 0xFFFF0000u;
    float r0 = x0 - __uint_as_float(h0);
    float r1 = x1 - __uint_as_float(h1);
    hi = (h0 >> 16) | h1;
    lo = (__float_as_uint(r0) >> 16) | (__float_as_uint(r1) & 0xFFFF0000u);
}

__device__ __forceinline__ void split1(float x, unsigned short& hi, unsigned short& lo)
{
    unsigned u = __float_as_uint(x);
    unsigned h = u & 0xFFFF0000u;
    float r = x - __uint_as_float(h);
    hi = (unsigned short)(h >> 16);
    lo = (unsigned short)(__float_as_uint(r) >> 16);
}

__device__ __forceinline__ short8 ldfrag(const unsigned short* base, int row, int kuo)
{
    const unsigned long long* p =
        (const unsigned long long*)(base + row * LDS_KS + kuo);
    union { unsigned long long q[2]; short8 s; } u;
    u.q[0] = p[0];
    u.q[1] = p[1];
    return u.s;
}

__device__ __forceinline__ short8 ldfrag20(const unsigned short* base, int row, int kuo)
{
    const unsigned long long* p =
        (const unsigned long long*)(base + row * 20 + kuo);
    union { unsigned long long q[2]; short8 s; } u;
    u.q[0] = p[0];
    u.q[1] = p[1];
    return u.s;
}

// ---------------------------------------------------------------------------
// K2 (MFMA split-bf16): logical BcP[part][g*256+h*64+dd][j] = sum_k A*adj
// Epilogue writes split-bf16 TRANSPOSED planes:
//   Bhi/Blo[(g*4+h)][j][k]  (k = part*64+dd, k-contiguous rows of 128 ushorts)
// Rows j in [4900, 4904) zeroed; j >= 4904 nonexistent.
// ---------------------------------------------------------------------------
__global__ __launch_bounds__(256) void k2_mfma(
    const float* __restrict__ hK, const float* __restrict__ adj,
    const float* __restrict__ S,
    unsigned short* __restrict__ Bhi, unsigned short* __restrict__ Blo)
{
    __shared__ unsigned short sAh[128 * LDS_KS];
    __shared__ unsigned short sAl[128 * LDS_KS];
    __shared__ unsigned short sBh[64 * LDS_KS];
    __shared__ unsigned short sBl[64 * LDS_KS];

    int t = threadIdx.x;
    int j0 = blockIdx.x * 64;
    int h  = blockIdx.y;
    int part = blockIdx.z;
    int L = part ? NG2 : NG1;
    const float* kflat = hK + (part ? (size_t)NG1 * OUTF : 0);
    int rowoff = part ? NG1 : 0;

    int dd = t & 63;          // staging lane: dd for A, n for B
    int kg = t >> 6;          // k-group 0..3 (== wave id)
    int jcol = j0 + dd;

    float sc[2][4];
#pragma unroll
    for (int g = 0; g < 2; ++g)
#pragma unroll
        for (int c = 0; c < 4; ++c)
            sc[g][c] = 0.5f * S[(g + part) * 256 + c * 64 + dd];

    f32x16 acc0, acc1;
#pragma unroll
    for (int i = 0; i < 16; ++i) { acc0[i] = 0.f; acc1[i] = 0.f; }

    int lane = t & 63;
    int half = lane >> 5;
    int ml = lane & 31;
    int arow = kg * 32 + ml;

    unsigned* uAh = (unsigned*)sAh;
    unsigned* uAl = (unsigned*)sAl;
    unsigned* uBh = (unsigned*)sBh;
    unsigned* uBl = (unsigned*)sBl;

    int Ksteps = (L + 31) >> 5;
    for (int ks = 0; ks < Ksteps; ++ks) {
        int k0 = ks * 32;
        float xa[8], xb[8];
#pragma unroll
        for (int i = 0; i < 8; ++i) {
            int kv = k0 + kg * 8 + i;
            bool okk = (kv < L);
            xa[i] = okk ? kflat[(size_t)(h * L + kv) * 64 + dd] : 0.f;
            xb[i] = (okk && jcol < NPOS)
                        ? adj[(size_t)(rowoff + kv) * NPOS + jcol] : 0.f;
        }
        unsigned hA0[4], lA0[4], hA1[4], lA1[4], hB[4], lB[4];
#pragma unroll
        for (int i = 0; i < 8; i += 2) {
            float a0 = xa[i] * sc[0][i & 3];
            float a1 = xa[i + 1] * sc[0][(i + 1) & 3];
            split2(a0, a1, hA0[i >> 1], lA0[i >> 1]);
            float c0 = xa[i] * sc[1][i & 3];
            float c1 = xa[i + 1] * sc[1][(i + 1) & 3];
            split2(c0, c1, hA1[i >> 1], lA1[i >> 1]);
            split2(xb[i], xb[i + 1], hB[i >> 1], lB[i >> 1]);
        }
        __syncthreads();
        {
            int b0 = dd * 18 + kg * 4;
            int b1 = (64 + dd) * 18 + kg * 4;
            *(uint2*)(uAh + b0)     = make_uint2(hA0[0], hA0[1]);
            *(uint2*)(uAh + b0 + 2) = make_uint2(hA0[2], hA0[3]);
            *(uint2*)(uAl + b0)     = make_uint2(lA0[0], lA0[1]);
            *(uint2*)(uAl + b0 + 2) = make_uint2(lA0[2], lA0[3]);
            *(uint2*)(uAh + b1)     = make_uint2(hA1[0], hA1[1]);
            *(uint2*)(uAh + b1 + 2) = make_uint2(hA1[2], hA1[3]);
            *(uint2*)(uAl + b1)     = make_uint2(lA1[0], lA1[1]);
            *(uint2*)(uAl + b1 + 2) = make_uint2(lA1[2], lA1[3]);
            *(uint2*)(uBh + b0)     = make_uint2(hB[0], hB[1]);
            *(uint2*)(uBh + b0 + 2) = make_uint2(hB[2], hB[3]);
            *(uint2*)(uBl + b0)     = make_uint2(lB[0], lB[1]);
            *(uint2*)(uBl + b0 + 2) = make_uint2(lB[2], lB[3]);
        }
        __syncthreads();
#pragma unroll
        for (int kq = 0; kq < 2; ++kq) {
            int kuo = kq * 16 + half * 8;
            short8 aH = ldfrag(sAh, arow, kuo);
            short8 aL = ldfrag(sAl, arow, kuo);
            short8 b0H = ldfrag(sBh, ml, kuo);
            short8 b0L = ldfrag(sBl, ml, kuo);
            short8 b1H = ldfrag(sBh, 32 + ml, kuo);
            short8 b1L = ldfrag(sBl, 32 + ml, kuo);
            acc0 = __builtin_amdgcn_mfma_f32_32x32x16_bf16(aH, b0H, acc0, 0, 0, 0);
            acc0 = __builtin_amdgcn_mfma_f32_32x32x16_bf16(aH, b0L, acc0, 0, 0, 0);
            acc0 = __builtin_amdgcn_mfma_f32_32x32x16_bf16(aL, b0H, acc0, 0, 0, 0);
            acc1 = __builtin_amdgcn_mfma_f32_32x32x16_bf16(aH, b1H, acc1, 0, 0, 0);
            acc1 = __builtin_amdgcn_mfma_f32_32x32x16_bf16(aH, b1L, acc1, 0, 0, 0);
            acc1 = __builtin_amdgcn_mfma_f32_32x32x16_bf16(aL, b1H, acc1, 0, 0, 0);
        }
    }

    // epilogue: split-bf16 transposed store to B' [gh][j][k], k = part*64+dd
    int col0 = j0 + ml;        // <= 4895 < NPOS always
    int col1 = j0 + 32 + ml;   // may exceed
#pragma unroll
    for (int reg = 0; reg < 16; ++reg) {
        int m = kg * 32 + (reg & 3) + 8 * (reg >> 2) + 4 * half;
        int g = m >> 6, ddm = m & 63;
        size_t base = ((size_t)(g * 4 + h) * JB) * 128 + part * 64 + ddm;
        unsigned short hi0, lo0;
        split1(acc0[reg], hi0, lo0);
        Bhi[base + (size_t)col0 * 128] = hi0;
        Blo[base + (size_t)col0 * 128] = lo0;
        if (col1 < JB) {
            float v1 = (col1 < NPOS) ? acc1[reg] : 0.f;
            unsigned short hi1, lo1;
            split1(v1, hi1, lo1);
            Bhi[base + (size_t)col1 * 128] = hi1;
            Blo[base + (size_t)col1 * 128] = lo1;
        }
    }
}

// ---------------------------------------------------------------------------
// K3a (MFMA split-bf16): LG[h][pos][jloc] = Q~[h,pos][0:128] . B'[gh][j][0:128]
// Tile M=128 q x N=128 j x K=128.  4 waves in 2x2, each wave 2m x 2n 32-tiles.
// A staged from hQ*S with on-the-fly split; B staged as ushort copies from B'.
// LDS rows: 16 k-ushorts @ stride 20 (2-way bank alias = free).
// ---------------------------------------------------------------------------
__global__ __launch_bounds__(256) void k3a_mfma(
    const float* __restrict__ hQ, const float* __restrict__ S,
    const unsigned short* __restrict__ Bhi, const unsigned short* __restrict__ Blo,
    float* __restrict__ LG, int j0)
{
    __shared__ __align__(16) unsigned short sA[2][128 * 20];  // [hi/lo][m][k16]
    __shared__ __align__(16) unsigned short sB[2][128 * 20];  // [hi/lo][j][k16]

    int t = threadIdx.x;
    int n0 = blockIdx.x * 128;       // 0,128,256 within slab
    int y = blockIdx.y;              // 156 = 4h * 39
    int h = y / 39, rr = y % 39;
    int g, tile;
    if (rr < 6) { g = 0; tile = rr; } else { g = 1; tile = rr - 6; }
    int Lg = g ? NG2 : NG1;
    int vbase = g ? NG1 * OUTF : 0;
    int posbase = g ? NG1 : 0;
    int q0 = tile * 128;

    int w = t >> 6, lane = t & 63;
    int half = lane >> 5, ml = lane & 31;
    int wm = w >> 1, wn = w & 1;

    f32x16 acc[2][2];
#pragma unroll
    for (int i = 0; i < 2; ++i)
#pragma unroll
        for (int j = 0; j < 2; ++j)
#pragma unroll
            for (int r = 0; r < 16; ++r) acc[i][j][r] = 0.f;

    // staging coords
    int mA = t >> 1, khA = t & 1;            // A: row m, k-half
    int jB = t & 127, plB = t >> 7;          // B: row j, plane
    size_t bplaneoff = (size_t)(g * 4 + h) * JB * 128;
    const unsigned short* bsrc = (plB ? Blo : Bhi) + bplaneoff;
    int jglob = j0 + n0 + jB;

    for (int kf = 0; kf < 8; ++kf) {
        int p = kf >> 2;
        int dA = (kf & 3) * 16 + khA * 8;    // d within 64-half
        // --- global prefetch ---
        float x[8];
        {
            int ql = q0 + mA;
            if (ql < Lg) {
                const float* qp = hQ + vbase + (size_t)(h * Lg + ql) * 64 + dA;
                const float* sp = S + (g + p) * 256 + (ql & 3) * 64 + dA;
                float4 q0v = ((const float4*)qp)[0];
                float4 q1v = ((const float4*)qp)[1];
                float4 s0v = ((const float4*)sp)[0];
                float4 s1v = ((const float4*)sp)[1];
                x[0] = q0v.x * s0v.x; x[1] = q0v.y * s0v.y;
                x[2] = q0v.z * s0v.z; x[3] = q0v.w * s0v.w;
                x[4] = q1v.x * s1v.x; x[5] = q1v.y * s1v.y;
                x[6] = q1v.z * s1v.z; x[7] = q1v.w * s1v.w;
            } else {
#pragma unroll
                for (int i = 0; i < 8; ++i) x[i] = 0.f;
            }
        }
        uint4 b0 = make_uint4(0, 0, 0, 0), b1 = make_uint4(0, 0, 0, 0);
        if (jglob < JB) {
            const uint4* bp = (const uint4*)(bsrc + (size_t)jglob * 128 + kf * 16);
            b0 = bp[0];
            b1 = bp[1];
        }
        unsigned hiA[4], loA[4];
#pragma unroll
        for (int i = 0; i < 4; ++i)
            split2(x[2 * i], x[2 * i + 1], hiA[i], loA[i]);

        __syncthreads();   // prev frag reads done
        {
            unsigned* pAh = (unsigned*)(sA[0] + mA * 20 + khA * 8);
            unsigned* pAl = (unsigned*)(sA[1] + mA * 20 + khA * 8);
            *(uint2*)pAh       = make_uint2(hiA[0], hiA[1]);
            *(uint2*)(pAh + 2) = make_uint2(hiA[2], hiA[3]);
            *(uint2*)pAl       = make_uint2(loA[0], loA[1]);
            *(uint2*)(pAl + 2) = make_uint2(loA[2], loA[3]);
            unsigned* pB = (unsigned*)(sB[plB] + jB * 20);
            *(uint2*)pB       = make_uint2(b0.x, b0.y);
            *(uint2*)(pB + 2) = make_uint2(b0.z, b0.w);
            *(uint2*)(pB + 4) = make_uint2(b1.x, b1.y);
            *(uint2*)(pB + 6) = make_uint2(b1.z, b1.w);
        }
        __syncthreads();   // staging visible

        short8 aH[2], aL[2], bH[2], bL[2];
#pragma unroll
        for (int i = 0; i < 2; ++i) {
            int mrow = (2 * wm + i) * 32 + ml;
            aH[i] = ldfrag20(sA[0], mrow, half * 8);
            aL[i] = ldfrag20(sA[1], mrow, half * 8);
            int nrow = (2 * wn + i) * 32 + ml;
            bH[i] = ldfrag20(sB[0], nrow, half * 8);
            bL[i] = ldfrag20(sB[1], nrow, half * 8);
        }
#pragma unroll
        for (int mi = 0; mi < 2; ++mi)
#pragma unroll
            for (int ni = 0; ni < 2; ++ni) {
                acc[mi][ni] = __builtin_amdgcn_mfma_f32_32x32x16_bf16(aH[mi], bH[ni], acc[mi][ni], 0, 0, 0);
                acc[mi][ni] = __builtin_amdgcn_mfma_f32_32x32x16_bf16(aH[mi], bL[ni], acc[mi][ni], 0, 0, 0);
                acc[mi][ni] = __builtin_amdgcn_mfma_f32_32x32x16_bf16(aL[mi], bH[ni], acc[mi][ni], 0, 0, 0);
            }
    }

    // epilogue: C/D layout col=lane&31, row=(reg&3)+8*(reg>>2)+4*(lane>>5)
#pragma unroll
    for (int mi = 0; mi < 2; ++mi) {
        int mtile = (2 * wm + mi) * 32;
#pragma unroll
        for (int reg = 0; reg < 16; ++reg) {
            int mloc = mtile + (reg & 3) + 8 * (reg >> 2) + 4 * half;
            int ql = q0 + mloc;
            if (ql < Lg) {
                float* dst = LG + ((size_t)h * NPOS + posbase + ql) * JS + n0;
#pragma unroll
                for (int ni = 0; ni < 2; ++ni) {
                    int nloc = (2 * wn + ni) * 32 + ml;
                    dst[nloc] = acc[mi][ni][reg];
                }
            }
        }
    }
}

// ---------------------------------------------------------------------------
// K3b: PV slab GEMM, ALL 4 heads per block (LG read exactly once).
// ---------------------------------------------------------------------------
__global__ __launch_bounds__(256) void k3b_pv(
    const float* __restrict__ LG, const float* __restrict__ hV,
    float* __restrict__ mpart, int j0, int first)
{
    __shared__ float Asm[4][16][34];   // [h][jj][pos]  alpha
    __shared__ float Bsv[16][264];     // [jj][ch]      V
    int t = threadIdx.x;
    int m0 = blockIdx.x * 32;
    int ks = blockIdx.y;
    int jbase = ks * 192;

    float acc[2][16];
#pragma unroll
    for (int i = 0; i < 2; ++i)
#pragma unroll
        for (int j = 0; j < 16; ++j) acc[i][j] = 0.f;
    int pos2 = (t & 15) * 2;
    int ch16 = (t >> 4) * 16;
    int hch  = ch16 >> 6;
    int sj = t & 15, sp = t >> 4;

    for (int kc = 0; kc < 192; kc += 16) {
        __syncthreads();
#pragma unroll
        for (int i = 0; i < 4; ++i) {
            int s = t + i * 256;
            int jj = s >> 6, c4 = (s & 63) * 4;
            int h = c4 >> 6, d = c4 & 63;
            int jglob = j0 + jbase + kc + jj;
            float4 x = make_float4(0.f, 0.f, 0.f, 0.f);
            if (jglob < NPOS)
                x = *(const float4*)(hV + ((size_t)h * NPOS + jglob) * 64 + d);
            *(float4*)&Bsv[jj][c4] = x;
        }
#pragma unroll
        for (int i = 0; i < 2; ++i) {
            int posl = sp + 16 * i;
            int pos = m0 + posl;
            int jglob = j0 + jbase + kc + sj;
            float v0 = 0.f, v1 = 0.f, v2 = 0.f, v3 = 0.f;
            if (pos < NPOS) {
                size_t base = (size_t)pos * JS + jbase + kc + sj;
                v0 = LG[base];
                v1 = LG[(size_t)NPOS * JS + base];
                v2 = LG[(size_t)2 * NPOS * JS + base];
                v3 = LG[(size_t)3 * NPOS * JS + base];
            }
            float mx = fmaxf(fmaxf(v0, v1), fmaxf(v2, v3));
            float e0 = __expf(v0 - mx), e1 = __expf(v1 - mx);
            float e2 = __expf(v2 - mx), e3 = __expf(v3 - mx);
            float inv = 1.0f / (e0 + e1 + e2 + e3);
            bool ok = (pos < NPOS) && (jglob < NPOS);
            float z = ok ? inv : 0.f;
            Asm[0][sj][posl] = e0 * z;
            Asm[1][sj][posl] = e1 * z;
            Asm[2][sj][posl] = e2 * z;
            Asm[3][sj][posl] = e3 * z;
        }
        __syncthreads();
#pragma unroll
        for (int kk = 0; kk < 16; ++kk) {
            float2 a = *(const float2*)&Asm[hch][kk][pos2];
            float4 b0 = *(const float4*)&Bsv[kk][ch16 + 0];
            float4 b1 = *(const float4*)&Bsv[kk][ch16 + 4];
            float4 b2 = *(const float4*)&Bsv[kk][ch16 + 8];
            float4 b3 = *(const float4*)&Bsv[kk][ch16 + 12];
            float bv_[16] = {b0.x, b0.y, b0.z, b0.w, b1.x, b1.y, b1.z, b1.w,
                             b2.x, b2.y, b2.z, b2.w, b3.x, b3.y, b3.z, b3.w};
#pragma unroll
            for (int j = 0; j < 16; ++j) {
                acc[0][j] += a.x * bv_[j];
                acc[1][j] += a.y * bv_[j];
            }
        }
    }
#pragma unroll
    for (int i = 0; i < 2; ++i) {
        int pos = m0 + pos2 + i;
        if (pos < NPOS) {
            float* pp = mpart + ((size_t)ks * NPOS + pos) * OUTF + ch16;
#pragma unroll
            for (int c = 0; c < 16; c += 4) {
                float4 prev = first ? make_float4(0.f, 0.f, 0.f, 0.f)
                                    : *(const float4*)(pp + c);
                *(float4*)(pp + c) = make_float4(prev.x + acc[i][c + 0],
                                                 prev.y + acc[i][c + 1],
                                                 prev.z + acc[i][c + 2],
                                                 prev.w + acc[i][c + 3]);
            }
        }
    }
}

// ---------------------------------------------------------------------------
// E1: m = mpart0+mpart1; relu; ln1; write concat buffer [H | ln1(relu(m))]
// ---------------------------------------------------------------------------
__global__ __launch_bounds__(256) void e1_relu_ln(
    const float* __restrict__ mpart, const float* __restrict__ Hb,
    const float* __restrict__ g1, const float* __restrict__ b1,
    float* __restrict__ cc)
{
    int w = threadIdx.x >> 6, lane = threadIdx.x & 63;
    int row = blockIdx.x * 4 + w;
    int c = lane * 4;
    float4 x0 = *(const float4*)(mpart + (size_t)row * OUTF + c);
    float4 x1 = *(const float4*)(mpart + (size_t)NPOS * OUTF + (size_t)row * OUTF + c);
    float x[4] = { fmaxf(x0.x + x1.x, 0.f), fmaxf(x0.y + x1.y, 0.f),
                   fmaxf(x0.z + x1.z, 0.f), fmaxf(x0.w + x1.w, 0.f) };
    float s = x[0] + x[1] + x[2] + x[3];
#pragma unroll
    for (int m = 32; m > 0; m >>= 1) s += __shfl_xor(s, m, 64);
    float mu = s * (1.0f / 256.0f);
    float vs = 0.f;
#pragma unroll
    for (int i = 0; i < 4; ++i) { float d = x[i] - mu; vs += d * d; }
#pragma unroll
    for (int m = 32; m > 0; m >>= 1) vs += __shfl_xor(vs, m, 64);
    float rs = rsqrtf(vs * (1.0f / 256.0f) + 1e-5f);
    float4 y;
    y.x = (x[0] - mu) * rs * g1[c + 0] + b1[c + 0];
    y.y = (x[1] - mu) * rs * g1[c + 1] + b1[c + 1];
    y.z = (x[2] - mu) * rs * g1[c + 2] + b1[c + 2];
    y.w = (x[3] - mu) * rs * g1[c + 3] + b1[c + 3];
    *(float4*)(cc + (size_t)row * INF + OUTF + c) = y;
    float4 hh = *(const float4*)(Hb + (size_t)row * OUTF + c);
    *(float4*)(cc + (size_t)row * INF + c) = hh;
}

// ---------------------------------------------------------------------------
// E2: beta = sigmoid(cc @ Wbeta + bbeta); out = beta*m1 + (1-beta)*H
// ---------------------------------------------------------------------------
__global__ __launch_bounds__(256) void e2_beta(
    const float* __restrict__ cc, const float* __restrict__ Wb,
    const float* __restrict__ bb, float* __restrict__ outb)
{
    __shared__ float AT[16][68];
    __shared__ float Bs[16][132];
    int t = threadIdx.x;
    int n0 = blockIdx.x * 128;
    int m0 = blockIdx.y * 64;
    float acc[4][8];
#pragma unroll
    for (int i = 0; i < 4; ++i)
#pragma unroll
        for (int j = 0; j < 8; ++j) acc[i][j] = 0.f;
    int mg = (t >> 4) * 4, jg = (t & 15) * 8;
    int am = t & 63, ak = (t >> 6) * 4;
    int bkk = t >> 4, bn = (t & 15) * 8;
    for (int k0 = 0; k0 < INF; k0 += 16) {
        __syncthreads();
        {
            int row = m0 + am;
            float4 v = make_float4(0.f, 0.f, 0.f, 0.f);
            if (row < NPOS) v = *(const float4*)(cc + (size_t)row * INF + k0 + ak);
            AT[ak + 0][am] = v.x; AT[ak + 1][am] = v.y;
            AT[ak + 2][am] = v.z; AT[ak + 3][am] = v.w;
        }
        {
            const float* p = Wb + (size_t)(k0 + bkk) * OUTF + n0 + bn;
            float4 u0 = *(const float4*)p;
            float4 u1 = *(const float4*)(p + 4);
            *(float4*)&Bs[bkk][bn]     = u0;
            *(float4*)&Bs[bkk][bn + 4] = u1;
        }
        __syncthreads();
#pragma unroll
        for (int kk = 0; kk < 16; ++kk) {
            float4 a  = *(const float4*)&AT[kk][mg];
            float4 b0 = *(const float4*)&Bs[kk][jg];
            float4 b1 = *(const float4*)&Bs[kk][jg + 4];
            float av[4] = {a.x, a.y, a.z, a.w};
            float bv_[8] = {b0.x, b0.y, b0.z, b0.w, b1.x, b1.y, b1.z, b1.w};
#pragma unroll
            for (int i = 0; i < 4; ++i)
#pragma unroll
                for (int j = 0; j < 8; ++j) acc[i][j] += av[i] * bv_[j];
        }
    }
#pragma unroll
    for (int i = 0; i < 4; ++i) {
        int row = m0 + mg + i;
        if (row < NPOS) {
#pragma unroll
            for (int j = 0; j < 8; ++j) {
                int n = n0 + jg + j;
                float x = acc[i][j] + bb[n];
                float sg = 1.0f / (1.0f + __expf(-x));
                float m1v = cc[(size_t)row * INF + OUTF + n];
                float Hv  = cc[(size_t)row * INF + n];
                outb[(size_t)row * OUTF + n] = sg * m1v + (1.0f - sg) * Hv;
            }
        }
    }
}

// ---------------------------------------------------------------------------
// E3: t = out @ w1 + b1 ; ln2(eps=1e-6) ; tanh -> h2.
// ---------------------------------------------------------------------------
__global__ __launch_bounds__(256) void e3_w1_ln2(
    const float* __restrict__ outb, const float* __restrict__ w1,
    const float* __restrict__ b1v, const float* __restrict__ g2,
    const float* __restrict__ b2v, float* __restrict__ h2o)
{
    __shared__ float As[16][260];
    __shared__ float Bs[16][260];
    __shared__ float red[16][17];
    int t = threadIdx.x;
    int m0 = blockIdx.x * 16;
    {
        int rr = t >> 4, c4 = (t & 15) * 4;
        int row = m0 + rr;
#pragma unroll
        for (int i = 0; i < 4; ++i) {
            int c = c4 + i * 64;
            float4 x = make_float4(0.f, 0.f, 0.f, 0.f);
            if (row < NPOS) x = *(const float4*)(outb + (size_t)row * OUTF + c);
            *(float4*)&As[rr][c] = x;
        }
    }
    int q = t & 15, dg = (t >> 4) * 16;
    float acc[16];
#pragma unroll
    for (int i = 0; i < 16; ++i) acc[i] = 0.f;
    for (int k0 = 0; k0 < 256; k0 += 16) {
        __syncthreads();
        {
            int kk = t >> 4, n16 = (t & 15) * 16;
#pragma unroll
            for (int i = 0; i < 4; ++i) {
                float4 x = *(const float4*)(w1 + (size_t)(k0 + kk) * OUTF + n16 + i * 4);
                *(float4*)&Bs[kk][n16 + i * 4] = x;
            }
        }
        __syncthreads();
#pragma unroll
        for (int kk = 0; kk < 16; ++kk) {
            float a = As[q][k0 + kk];
#pragma unroll
            for (int i = 0; i < 16; i += 4) {
                float4 b = *(const float4*)&Bs[kk][dg + i];
                acc[i + 0] += a * b.x; acc[i + 1] += a * b.y;
                acc[i + 2] += a * b.z; acc[i + 3] += a * b.w;
            }
        }
    }
    float x[16];
#pragma unroll
    for (int i = 0; i < 16; ++i) x[i] = acc[i] + b1v[dg + i];
    float ps = 0.f;
#pragma unroll
    for (int i = 0; i < 16; ++i) ps += x[i];
    __syncthreads();
    red[t >> 4][q] = ps;
    __syncthreads();
    float s = 0.f;
#pragma unroll
    for (int i = 0; i < 16; ++i) s += red[i][q];
    float mu = s * (1.0f / 256.0f);
    float pv = 0.f;
#pragma unroll
    for (int i = 0; i < 16; ++i) { float d = x[i] - mu; pv += d * d; }
    __syncthreads();
    red[t >> 4][q] = pv;
    __syncthreads();
    float v = 0.f;
#pragma unroll
    for (int i = 0; i < 16; ++i) v += red[i][q];
    float rs = rsqrtf(v * (1.0f / 256.0f) + 1e-6f);
    int row = m0 + q;
    if (row < NPOS) {
#pragma unroll
        for (int i = 0; i < 16; ++i) {
            int n = dg + i;
            h2o[(size_t)row * OUTF + n] = tanhf((x[i] - mu) * rs * g2[n] + b2v[n]);
        }
    }
}

// ---------------------------------------------------------------------------
// E4: final = h2 @ w2  (no bias) -> d_out
// ---------------------------------------------------------------------------
__global__ __launch_bounds__(256) void e4_final(
    const float* __restrict__ h2in, const float* __restrict__ w2,
    float* __restrict__ outp)
{
    __shared__ float AT[16][68];
    __shared__ float Bs[16][132];
    int t = threadIdx.x;
    int n0 = blockIdx.x * 128;
    int m0 = blockIdx.y * 64;
    float acc[4][8];
#pragma unroll
    for (int i = 0; i < 4; ++i)
#pragma unroll
        for (int j = 0; j < 8; ++j) acc[i][j] = 0.f;
    int mg = (t >> 4) * 4, jg = (t & 15) * 8;
    int am = t & 63, ak = (t >> 6) * 4;
    int bkk = t >> 4, bn = (t & 15) * 8;
    for (int k0 = 0; k0 < 256; k0 += 16) {
        __syncthreads();
        {
            int row = m0 + am;
            float4 v = make_float4(0.f, 0.f, 0.f, 0.f);
            if (row < NPOS) v = *(const float4*)(h2in + (size_t)row * OUTF + k0 + ak);
            AT[ak + 0][am] = v.x; AT[ak + 1][am] = v.y;
            AT[ak + 2][am] = v.z; AT[ak + 3][am] = v.w;
        }
        {
            const float* p = w2 + (size_t)(k0 + bkk) * OUTF + n0 + bn;
            float4 u0 = *(const float4*)p;
            float4 u1 = *(const float4*)(p + 4);
            *(float4*)&Bs[bkk][bn]     = u0;
            *(float4*)&Bs[bkk][bn + 4] = u1;
        }
        __syncthreads();
#pragma unroll
        for (int kk = 0; kk < 16; ++kk) {
            float4 a  = *(const float4*)&AT[kk][mg];
            float4 b0 = *(const float4*)&Bs[kk][jg];
            float4 b1 = *(const float4*)&Bs[kk][jg + 4];
            float av[4] = {a.x, a.y, a.z, a.w};
            float bv_[8] = {b0.x, b0.y, b0.z, b0.w, b1.x, b1.y, b1.z, b1.w};
#pragma unroll
            for (int i = 0; i < 4; ++i)
#pragma unroll
                for (int j = 0; j < 8; ++j) acc[i][j] += av[i] * bv_[j];
        }
    }
#pragma unroll
    for (int i = 0; i < 4; ++i) {
        int row = m0 + mg + i;
        if (row < NPOS) {
#pragma unroll
            for (int j = 0; j < 8; ++j) {
                outp[(size_t)row * OUTF + n0 + jg + j] = acc[i][j];
            }
        }
    }
}

// ---------------------------------------------------------------------------
extern "C" void kernel_launch(void* const* d_in, const int* in_sizes, int n_in,
                              void* d_out, int out_size, void* d_ws, size_t ws_size,
                              hipStream_t stream)
{
    const float* feature = (const float*)d_in[0];
    const float* adj   = (const float*)d_in[1];
    const float* r     = (const float*)d_in[2];
    const float* Wq    = (const float*)d_in[3];
    const float* bq    = (const float*)d_in[4];
    const float* Wk    = (const float*)d_in[5];
    const float* bk    = (const float*)d_in[6];
    const float* Wv    = (const float*)d_in[7];
    const float* bv    = (const float*)d_in[8];
    const float* Ww    = (const float*)d_in[9];
    const float* bw    = (const float*)d_in[10];
    const float* Wr    = (const float*)d_in[11];
    const float* br    = (const float*)d_in[12];
    const float* Wbeta = (const float*)d_in[13];
    const float* bbeta = (const float*)d_in[14];
    const float* ln1g  = (const float*)d_in[15];
    const float* ln1b  = (const float*)d_in[16];
    const float* w1    = (const float*)d_in[17];
    const float* b1    = (const float*)d_in[18];
    const float* ln2g  = (const float*)d_in[19];
    const float* ln2b  = (const float*)d_in[20];
    const float* w2    = (const float*)d_in[21];
    const int*   flag  = (const int*)d_in[22];
    float* out = (float*)d_out;

    // --- workspace layout (liveness-aliased; identical extents to round 5) ---
    char* ws = (char*)d_ws;
    float*          LG    = (float*)(ws + 0);            // 30,105,600
    float*          hQ    = (float*)(ws + 30130176);
    float*          hK    = (float*)(ws + 35147776);
    float*          cc    = (float*)(ws + 30130176);
    float*          hV    = (float*)(ws + 40165376);
    float*          outb  = (float*)(ws + 40165376);
    float*          Hb    = (float*)(ws + 45182976);
    float*          hh2   = (float*)(ws + 45182976);
    unsigned short* Bhi   = (unsigned short*)(ws + 50200576);  // 10,043,392
    unsigned short* Blo   = (unsigned short*)(ws + 60243968);  // 10,043,392
    float*          mpart = (float*)(ws + 70287360);
    float*          S     = (float*)(ws + 80322560);

    k0_rp<<<1, 256, 0, stream>>>(r, Wr, br, flag, S);
    k1_proj<<<dim3(8, 77), 256, 0, stream>>>(feature, Wq, bq, Wk, bk, Wv, bv, Ww, bw,
                                             hQ, hK, hV, Hb);
    k2_mfma<<<dim3(77, 4, 2), 256, 0, stream>>>(hK, adj, S, Bhi, Blo);
    for (int s = 0; s < NSLAB; ++s) {
        int j0 = s * JS;
        k3a_mfma<<<dim3(3, 156), 256, 0, stream>>>(hQ, S, Bhi, Blo, LG, j0);
        k3b_pv<<<dim3(154, 2), 256, 0, stream>>>(LG, hV, mpart, j0, s == 0 ? 1 : 0);
    }
    e1_relu_ln<<<1225, 256, 0, stream>>>(mpart, Hb, ln1g, ln1b, cc);
    e2_beta<<<dim3(2, 77), 256, 0, stream>>>(cc, Wbeta, bbeta, outb);
    e3_w1_ln2<<<307, 256, 0, stream>>>(outb, w1, b1, ln2g, ln2b, hh2);
    e4_final<<<dim3(2, 77), 256, 0, stream>>>(hh2, w2, out);
}